// Round 6
// baseline (289.976 us; speedup 1.0000x reference)
//
#include <hip/hip_runtime.h>

#define TOTAL   160
#define NMAX    16
#define INDIM   1024
#define DIN     834
#define KPAD    864
#define GF      256
#define SS      1568
#define SPAD    1664   // 13 * 128
#define CROW    264    // ctx LDS row stride in shorts (256 + 8 pad)

__constant__ int c_counts[16] = {6,14,10,8,16,12,9,11,7,13,10,10,8,12,6,8};
__constant__ int c_offs[16]   = {0,6,20,30,38,54,66,75,86,93,106,116,126,134,146,152};
__constant__ int c_t0[8] = {0, 6, 12, 18, 25, 31, 37, 43};   // s-tile ranges (49 tiles of 32)
__constant__ int c_t1[8] = {6, 12, 18, 25, 31, 37, 43, 49};

// ragged row -> (batch, slot) lookup for the fused combine+head epilogue
__constant__ unsigned char c_b_of_t[160] = {
  0,0,0,0,0,0,
  1,1,1,1,1,1,1,1,1,1,1,1,1,1,
  2,2,2,2,2,2,2,2,2,2,
  3,3,3,3,3,3,3,3,
  4,4,4,4,4,4,4,4,4,4,4,4,4,4,4,4,
  5,5,5,5,5,5,5,5,5,5,5,5,
  6,6,6,6,6,6,6,6,6,
  7,7,7,7,7,7,7,7,7,7,7,
  8,8,8,8,8,8,8,
  9,9,9,9,9,9,9,9,9,9,9,9,9,
  10,10,10,10,10,10,10,10,10,10,
  11,11,11,11,11,11,11,11,11,11,
  12,12,12,12,12,12,12,12,
  13,13,13,13,13,13,13,13,13,13,13,13,
  14,14,14,14,14,14,
  15,15,15,15,15,15,15,15};
__constant__ unsigned char c_n_of_t[160] = {
  0,1,2,3,4,5,
  0,1,2,3,4,5,6,7,8,9,10,11,12,13,
  0,1,2,3,4,5,6,7,8,9,
  0,1,2,3,4,5,6,7,
  0,1,2,3,4,5,6,7,8,9,10,11,12,13,14,15,
  0,1,2,3,4,5,6,7,8,9,10,11,
  0,1,2,3,4,5,6,7,8,
  0,1,2,3,4,5,6,7,8,9,10,
  0,1,2,3,4,5,6,
  0,1,2,3,4,5,6,7,8,9,10,11,12,
  0,1,2,3,4,5,6,7,8,9,
  0,1,2,3,4,5,6,7,8,9,
  0,1,2,3,4,5,6,7,
  0,1,2,3,4,5,6,7,8,9,10,11,
  0,1,2,3,4,5,
  0,1,2,3,4,5,6,7};

using bf16x8 = __attribute__((ext_vector_type(8))) short;
using f32x4  = __attribute__((ext_vector_type(4))) float;
using f32x2  = __attribute__((ext_vector_type(2))) float;
using us4    = __attribute__((ext_vector_type(4))) unsigned short;

__device__ inline unsigned short f2bf(float f) {
  union { float f; unsigned u; } v; v.f = f;
  const unsigned u = v.u;
  return (unsigned short)((u + 0x7FFFu + ((u >> 16) & 1u)) >> 16);
}
__device__ inline float bf2f(unsigned short h) {
  union { unsigned u; float f; } v; v.u = ((unsigned)h) << 16; return v.f;
}

// direct global->LDS DMA, 16B per lane. lds dest is wave-uniform base + lane*16B.
__device__ __forceinline__ void gload16(const unsigned short* g, unsigned short* l) {
  __builtin_amdgcn_global_load_lds(
      (const __attribute__((address_space(1))) unsigned int*)(g),
      (__attribute__((address_space(3))) unsigned int*)(l), 16, 0, 0);
}

// ---------------- mega-fused front end ----------------
// blocks [0,48): emb bf16 MFMA; [48,3760): Wc/Wh pack; [3760,6784): fm transpose.
__global__ __launch_bounds__(256) void prep_all(
    const float* __restrict__ actor, const float* __restrict__ Wa,
    const float* __restrict__ b_a, const float* __restrict__ Wc,
    const float* __restrict__ Wh, const float* __restrict__ fm,
    float* __restrict__ emb, unsigned short* __restrict__ emb_h,
    unsigned short* __restrict__ Ah, unsigned short* __restrict__ Wh_h,
    unsigned short* __restrict__ BhT)
{
  __shared__ float tile[32][228];   // transpose staging (228 = 225 padded to x4 for float4 align)
  __shared__ unsigned short As[64 * 40];
  __shared__ unsigned short Bs[64 * 40];
  const int bid = blockIdx.x, tid = threadIdx.x;

  if (bid < 48) {
    // ---- emb: emb[m][n] = sum_k actor[m][k]*Wa[n][k] + b_a[n] ----
    const int n0 = (bid & 15) * 64, m0 = (bid >> 4) * 64;
    const int wave = tid >> 6, lane = tid & 63;
    const int wm = (wave >> 1) * 32, wn = (wave & 1) * 32;
    const int quad = lane >> 4, lr = lane & 15;
    const int r = tid >> 2, ko = (tid & 3) * 8;
    const bool mval = (m0 + r < TOTAL);

    f32x4 acc[2][2];
    #pragma unroll
    for (int i = 0; i < 2; ++i)
      #pragma unroll
      for (int j = 0; j < 2; ++j) acc[i][j] = (f32x4){0.f, 0.f, 0.f, 0.f};

    const float4 zf4 = {0.f, 0.f, 0.f, 0.f};
    float4 ra0, ra1, rb0, rb1;
    ra0 = mval ? *reinterpret_cast<const float4*>(actor + (size_t)(m0 + r) * INDIM + ko) : zf4;
    ra1 = mval ? *reinterpret_cast<const float4*>(actor + (size_t)(m0 + r) * INDIM + ko + 4) : zf4;
    rb0 = *reinterpret_cast<const float4*>(Wa + (size_t)(n0 + r) * INDIM + ko);
    rb1 = *reinterpret_cast<const float4*>(Wa + (size_t)(n0 + r) * INDIM + ko + 4);

    for (int kt = 0; kt < 32; ++kt) {
      __syncthreads();
      {
        us4 a0, a1, b0, b1;
        a0[0]=f2bf(ra0.x); a0[1]=f2bf(ra0.y); a0[2]=f2bf(ra0.z); a0[3]=f2bf(ra0.w);
        a1[0]=f2bf(ra1.x); a1[1]=f2bf(ra1.y); a1[2]=f2bf(ra1.z); a1[3]=f2bf(ra1.w);
        b0[0]=f2bf(rb0.x); b0[1]=f2bf(rb0.y); b0[2]=f2bf(rb0.z); b0[3]=f2bf(rb0.w);
        b1[0]=f2bf(rb1.x); b1[1]=f2bf(rb1.y); b1[2]=f2bf(rb1.z); b1[3]=f2bf(rb1.w);
        *reinterpret_cast<us4*>(&As[r * 40 + ko])     = a0;
        *reinterpret_cast<us4*>(&As[r * 40 + ko + 4]) = a1;
        *reinterpret_cast<us4*>(&Bs[r * 40 + ko])     = b0;
        *reinterpret_cast<us4*>(&Bs[r * 40 + ko + 4]) = b1;
      }
      __syncthreads();
      if (kt < 31) {
        const int k0 = (kt + 1) * 32;
        ra0 = mval ? *reinterpret_cast<const float4*>(actor + (size_t)(m0 + r) * INDIM + k0 + ko) : zf4;
        ra1 = mval ? *reinterpret_cast<const float4*>(actor + (size_t)(m0 + r) * INDIM + k0 + ko + 4) : zf4;
        rb0 = *reinterpret_cast<const float4*>(Wa + (size_t)(n0 + r) * INDIM + k0 + ko);
        rb1 = *reinterpret_cast<const float4*>(Wa + (size_t)(n0 + r) * INDIM + k0 + ko + 4);
      }
      bf16x8 af[2], bfr[2];
      #pragma unroll
      for (int i = 0; i < 2; ++i)
        af[i] = *reinterpret_cast<const bf16x8*>(&As[(wm + i * 16 + lr) * 40 + quad * 8]);
      #pragma unroll
      for (int j = 0; j < 2; ++j)
        bfr[j] = *reinterpret_cast<const bf16x8*>(&Bs[(wn + j * 16 + lr) * 40 + quad * 8]);
      #pragma unroll
      for (int i = 0; i < 2; ++i)
        #pragma unroll
        for (int j = 0; j < 2; ++j)
          acc[i][j] = __builtin_amdgcn_mfma_f32_16x16x32_bf16(af[i], bfr[j], acc[i][j], 0, 0, 0);
    }

    #pragma unroll
    for (int i = 0; i < 2; ++i) {
      #pragma unroll
      for (int reg = 0; reg < 4; ++reg) {
        const int m = m0 + wm + i * 16 + quad * 4 + reg;
        if (m >= TOTAL) continue;
        #pragma unroll
        for (int j = 0; j < 2; ++j) {
          const int n = n0 + wn + j * 16 + lr;
          const float v = acc[i][j][reg] + b_a[n];
          emb[(size_t)m * INDIM + n] = v;
          emb_h[(size_t)m * INDIM + n] = f2bf(v);
        }
      }
    }
  } else if (bid < 3760) {
    const int pb = bid - 48;
    if (pb < 3456) {
      const int idx = pb * 256 + tid;
      const int k = idx % KPAD, gm = idx / KPAD;
      Ah[idx] = (k < DIN) ? f2bf(Wc[gm * DIN + k]) : (unsigned short)0;
    } else {
      const int i = (pb - 3456) * 256 + tid;
      const float4 v = reinterpret_cast<const float4*>(Wh)[i];
      us4 o; o[0] = f2bf(v.x); o[1] = f2bf(v.y); o[2] = f2bf(v.z); o[3] = f2bf(v.w);
      reinterpret_cast<us4*>(Wh_h)[i] = o;
    }
  } else {
    // ---- fm [16][834][1568] fp32 -> BhT [16][1568][864] bf16 ----
    // k32 x s224 tiles: each fm row read is 896 B CONTIGUOUS (was 128 B) — attacks
    // the read side of the 83.7 MB fp32 stream (write side proven non-limiting r4/5).
    const int fb = bid - 3760;            // 0..3023 = 7 sx * 27 ky * 16 b
    const int sx = fb % 7, ky = (fb / 7) % 27, b = fb / 189;
    const int k0 = ky * 32, s0 = sx * 224;
    const int r = tid >> 3, c8 = tid & 7;
    const float* src = fm + (size_t)b * DIN * SS + (size_t)(k0 + r) * SS + s0;
    const bool kv = (k0 + r < DIN);
    const float4 zf = {0.f, 0.f, 0.f, 0.f};
    #pragma unroll
    for (int i = 0; i < 7; ++i) {
      const int c4 = c8 + 8 * i;          // float4 index 0..55
      const float4 v = kv ? *reinterpret_cast<const float4*>(src + c4 * 4) : zf;
      *reinterpret_cast<float4*>(&tile[r][c4 * 4]) = v;
    }
    __syncthreads();
    unsigned short* dstB = BhT + (size_t)b * SS * KPAD + (size_t)s0 * KPAD + k0;
    #pragma unroll
    for (int i = 0; i < 4; ++i) {
      const int idx = tid + 256 * i;
      if (idx < 896) {                    // 224 s-rows x 4 k-octets
        const int s = idx >> 2, q = idx & 3;
        uint4 o;
        o.x = (unsigned)f2bf(tile[q*8+0][s]) | ((unsigned)f2bf(tile[q*8+1][s]) << 16);
        o.y = (unsigned)f2bf(tile[q*8+2][s]) | ((unsigned)f2bf(tile[q*8+3][s]) << 16);
        o.z = (unsigned)f2bf(tile[q*8+4][s]) | ((unsigned)f2bf(tile[q*8+5][s]) << 16);
        o.w = (unsigned)f2bf(tile[q*8+6][s]) | ((unsigned)f2bf(tile[q*8+7][s]) << 16);
        *reinterpret_cast<uint4*>(dstB + (size_t)s * KPAD + q * 8) = o;
      }
    }
  }
}

// ---------------- ctx GEMM v3: 128x128 tile, 3-deep gload_lds ring, counted vmcnt ----------------
// At the 2-phase structural ceiling (~915 TF incl. tail, matches learn_hip m97 band); frozen.
__global__ __launch_bounds__(256, 3) void ctx_mfma(const unsigned short* __restrict__ Ah,
                                                   const unsigned short* __restrict__ BhT,
                                                   const float* __restrict__ b_c,
                                                   unsigned short* __restrict__ ctxT) {
  __shared__ unsigned short ABuf[3][2][4096];   // [ring][A|B][8KB] = 48 KiB -> 3 blocks/CU
  const int lin  = blockIdx.x;
  const int xcd  = lin & 7;
  const int slot = lin >> 3;                    // 0..207
  const int bloc = (slot >= 104) ? 1 : 0;
  const int within = slot - bloc * 104;         // 0..103
  const int b  = xcd * 2 + bloc;
  const int mt = within % 13;
  const int gn = within / 13;                   // 0..7
  const int g  = gn & 3;
  const int n0 = (gn >> 2) * 128;
  const int m0 = mt * 128;
  const int zout = (g << 4) + b;

  const int tid = threadIdx.x;
  const int w = tid >> 6, lane = tid & 63;
  const int wm = (w >> 1) * 64, wn = (w & 1) * 64;
  const int quad = lane >> 4, lr = lane & 15;

  const unsigned short* Ag = BhT + (size_t)b * SS * KPAD + (size_t)m0 * KPAD;
  const unsigned short* Bg = Ah + (size_t)g * 256 * KPAD + (size_t)n0 * KPAD;

  int rS[2], kS[2];
  #pragma unroll
  for (int p = 0; p < 2; ++p) {
    const int o    = p * 4096 + w * 1024 + lane * 16;
    const int line = o >> 7;
    const int gs   = (o >> 4) & 7;
    const int gg   = gs ^ (line & 7);
    rS[p] = line * 2 + (gg >> 2);
    kS[p] = (gg & 3) * 8;                       // shorts
  }

  int offA[4], offB[4];
  #pragma unroll
  for (int i = 0; i < 4; ++i) {
    const int r = wm + i * 16 + lr;
    const int line = r >> 1;
    const int gs = ((r & 1) * 4 + quad) ^ (line & 7);
    offA[i] = line * 64 + gs * 8;
  }
  #pragma unroll
  for (int j = 0; j < 4; ++j) {
    const int r = wn + j * 16 + lr;
    const int line = r >> 1;
    const int gs = ((r & 1) * 4 + quad) ^ (line & 7);
    offB[j] = line * 64 + gs * 8;
  }

  f32x4 acc[4][4];
  #pragma unroll
  for (int i = 0; i < 4; ++i)
    #pragma unroll
    for (int j = 0; j < 4; ++j) acc[i][j] = (f32x4){0.f, 0.f, 0.f, 0.f};

#define CTX_ISSUE(KT, BUF) {                                                          \
    _Pragma("unroll")                                                                 \
    for (int p = 0; p < 2; ++p) {                                                     \
      gload16(Ag + (size_t)rS[p] * KPAD + (KT) * 32 + kS[p],                          \
              &ABuf[BUF][0][p * 2048 + w * 512]);                                     \
      gload16(Bg + (size_t)rS[p] * KPAD + (KT) * 32 + kS[p],                          \
              &ABuf[BUF][1][p * 2048 + w * 512]);                                     \
    } }

#define CTX_BODY(KT, BUF, WAITSTR, DOISSUE) {                                         \
    asm volatile(WAITSTR ::: "memory");                                               \
    __builtin_amdgcn_s_barrier();               /* tile KT fully landed, all waves */ \
    bf16x8 af[4], bv[4];                                                              \
    _Pragma("unroll")                                                                 \
    for (int j = 0; j < 4; ++j)                                                       \
      bv[j] = *reinterpret_cast<const bf16x8*>(&ABuf[BUF][1][offB[j]]);               \
    _Pragma("unroll")                                                                 \
    for (int i = 0; i < 4; ++i)                                                       \
      af[i] = *reinterpret_cast<const bf16x8*>(&ABuf[BUF][0][offA[i]]);               \
    asm volatile("s_waitcnt lgkmcnt(0)" ::: "memory");                                \
    __builtin_amdgcn_sched_barrier(0);                                                \
    __builtin_amdgcn_s_barrier();               /* all reads of BUF complete */       \
    if (DOISSUE) CTX_ISSUE((KT) + 3, BUF);      /* refill just-freed buffer */        \
    _Pragma("unroll")                                                                 \
    for (int i = 0; i < 4; ++i)                                                       \
      _Pragma("unroll")                                                               \
      for (int j = 0; j < 4; ++j)                                                     \
        acc[i][j] = __builtin_amdgcn_mfma_f32_16x16x32_bf16(af[i], bv[j], acc[i][j], 0, 0, 0); \
  }

  CTX_ISSUE(0, 0);
  CTX_ISSUE(1, 1);
  CTX_ISSUE(2, 2);

  for (int kt = 0; kt < 24; kt += 3) {
    CTX_BODY(kt,     0, "s_waitcnt vmcnt(8)", 1);
    CTX_BODY(kt + 1, 1, "s_waitcnt vmcnt(8)", 1);
    CTX_BODY(kt + 2, 2, "s_waitcnt vmcnt(8)", 1);
  }
  CTX_BODY(24, 0, "s_waitcnt vmcnt(8)", 0);
  CTX_BODY(25, 1, "s_waitcnt vmcnt(4)", 0);
  CTX_BODY(26, 2, "s_waitcnt vmcnt(0)", 0);

#undef CTX_BODY
#undef CTX_ISSUE

  unsigned short* Cz = ctxT + (size_t)zout * SPAD * GF;
  const float* bias = b_c + g * GF;
  float bvj[4];
  #pragma unroll
  for (int j = 0; j < 4; ++j) bvj[j] = bias[n0 + wn + j * 16 + lr];
  #pragma unroll
  for (int i = 0; i < 4; ++i) {
    #pragma unroll
    for (int reg = 0; reg < 4; ++reg) {
      const int m = m0 + wm + i * 16 + quad * 4 + reg;
      #pragma unroll
      for (int j = 0; j < 4; ++j) {
        Cz[(size_t)m * GF + n0 + wn + j * 16 + lr] = f2bf(acc[i][j][reg] + bvj[j]);
      }
    }
  }
}

// ---------------- fused attention: logits MFMA + online softmax + PV (frozen r5) ----------------
__global__ __launch_bounds__(256) void att_part(
    const unsigned short* __restrict__ ctxT,
    const unsigned short* __restrict__ emb_h,
    float* __restrict__ Opart,     // [64*8][16][256]
    float* __restrict__ Spart)     // [64*8][32]: 16 M then 16 L
{
  __shared__ unsigned short Cs[4][32 * CROW];
  __shared__ float Ps[4][32][20];
  __shared__ float walpha[4][16];
  __shared__ float wms[4][16], wls[4][16];
  const int sc = blockIdx.x, z = blockIdx.y;
  const int g = z >> 4, b = z & 15;
  const int count = c_counts[b], off = c_offs[b];
  const int t0 = c_t0[sc], t1 = c_t1[sc];
  const int tid = threadIdx.x, wave = tid >> 6, lane = tid & 63;
  const int quad = lane >> 4, lr = lane & 15;
  const unsigned short* Az = ctxT + (size_t)z * SPAD * GF;
  const bool bvalid = (lr < count);
  const unsigned short* Brow = emb_h + (size_t)(off + (bvalid ? lr : 0)) * INDIM + (g << 8);
  unsigned short* myC = &Cs[wave][0];
  const int fbase = quad * 64 + lr * 4;
  const bf16x8 zero8 = (bf16x8)(short)0;

  f32x2 O2[16][2];
  #pragma unroll
  for (int n = 0; n < 16; ++n) {
    O2[n][0] = (f32x2){0.f, 0.f};
    O2[n][1] = (f32x2){0.f, 0.f};
  }
  float m_run = -3.0e38f, l_run = 0.f;

  for (int t = t0 + wave; t < t1; t += 4) {
    const int s0 = t * 32;
    #pragma unroll
    for (int q = 0; q < 16; ++q) {
      const int row = 2 * q + (lane >> 5);
      const int col = (lane & 31) * 8;
      const uint4 v = *reinterpret_cast<const uint4*>(Az + (size_t)(s0 + row) * GF + col);
      *reinterpret_cast<uint4*>(&myC[row * CROW + col]) = v;
    }
    f32x4 acc[2] = {(f32x4){0.f,0.f,0.f,0.f}, (f32x4){0.f,0.f,0.f,0.f}};
    #pragma unroll
    for (int kk = 0; kk < 8; ++kk) {
      const int f = kk * 32 + quad * 8;
      bf16x8 bv8 = *reinterpret_cast<const bf16x8*>(Brow + f);
      if (!bvalid) bv8 = zero8;
      #pragma unroll
      for (int i = 0; i < 2; ++i) {
        const bf16x8 av8 = *reinterpret_cast<const bf16x8*>(&myC[(i * 16 + lr) * CROW + f]);
        acc[i] = __builtin_amdgcn_mfma_f32_16x16x32_bf16(av8, bv8, acc[i], 0, 0, 0);
      }
    }
    float mx = acc[0][0];
    #pragma unroll
    for (int i = 0; i < 2; ++i)
      #pragma unroll
      for (int r = 0; r < 4; ++r) mx = fmaxf(mx, acc[i][r]);
    float lsum = 0.f;
    #pragma unroll
    for (int i = 0; i < 2; ++i)
      #pragma unroll
      for (int r = 0; r < 4; ++r) lsum += __expf(acc[i][r] - mx);
    #pragma unroll
    for (int d = 16; d < 64; d <<= 1) {
      const float om = __shfl_xor(mx, d, 64);
      const float ol = __shfl_xor(lsum, d, 64);
      const float M = fmaxf(mx, om);
      lsum = lsum * __expf(mx - M) + ol * __expf(om - M);
      mx = M;
    }
    const float m_new = fmaxf(m_run, mx);
    const float alpha = __expf(m_run - m_new);
    const float beta  = __expf(mx - m_new);
    l_run = alpha * l_run + beta * lsum;
    m_run = m_new;
    if (lane < 16) walpha[wave][lane] = alpha;
    #pragma unroll
    for (int i = 0; i < 2; ++i)
      #pragma unroll
      for (int r = 0; r < 4; ++r) {
        const int sl = i * 16 + quad * 4 + r;
        Ps[wave][sl][lr] = beta * __expf(acc[i][r] - mx);
      }
    float av[16];
    {
      const float4 a0 = *reinterpret_cast<const float4*>(&walpha[wave][0]);
      const float4 a1 = *reinterpret_cast<const float4*>(&walpha[wave][4]);
      const float4 a2 = *reinterpret_cast<const float4*>(&walpha[wave][8]);
      const float4 a3 = *reinterpret_cast<const float4*>(&walpha[wave][12]);
      av[0]=a0.x; av[1]=a0.y; av[2]=a0.z; av[3]=a0.w;
      av[4]=a1.x; av[5]=a1.y; av[6]=a1.z; av[7]=a1.w;
      av[8]=a2.x; av[9]=a2.y; av[10]=a2.z; av[11]=a2.w;
      av[12]=a3.x; av[13]=a3.y; av[14]=a3.z; av[15]=a3.w;
    }
    #pragma unroll
    for (int q = 0; q < 4; ++q) {
      if (q * 4 < count) {
        #pragma unroll
        for (int nn = 0; nn < 4; ++nn) {
          const int n = q * 4 + nn;
          O2[n][0] *= av[n];
          O2[n][1] *= av[n];
        }
      }
    }
    for (int s = 0; s < 32; ++s) {
      const us4 cv = *reinterpret_cast<const us4*>(&myC[s * CROW + fbase]);
      const f32x2 c01 = {bf2f(cv[0]), bf2f(cv[1])};
      const f32x2 c23 = {bf2f(cv[2]), bf2f(cv[3])};
      #pragma unroll
      for (int q = 0; q < 4; ++q) {
        if (q * 4 < count) {
          const float4 p = *reinterpret_cast<const float4*>(&Ps[wave][s][q * 4]);
          const float pq[4] = {p.x, p.y, p.z, p.w};
          #pragma unroll
          for (int nn = 0; nn < 4; ++nn) {
            const int n = q * 4 + nn;
            O2[n][0] += pq[nn] * c01;
            O2[n][1] += pq[nn] * c23;
          }
        }
      }
    }
  }

  if (lane < 16) { wms[wave][lane] = m_run; wls[wave][lane] = l_run; }
  __syncthreads();
  float* Ob = reinterpret_cast<float*>(&Cs[wave][0]);
  #pragma unroll
  for (int n = 0; n < 16; ++n) {
    const float Mb = fmaxf(fmaxf(wms[0][n], wms[1][n]), fmaxf(wms[2][n], wms[3][n]));
    const float e = __expf(wms[wave][n] - Mb);
    Ob[n * 256 + fbase + 0] = O2[n][0][0] * e;
    Ob[n * 256 + fbase + 1] = O2[n][0][1] * e;
    Ob[n * 256 + fbase + 2] = O2[n][1][0] * e;
    Ob[n * 256 + fbase + 3] = O2[n][1][1] * e;
  }
  __syncthreads();
  float* Op = Opart + ((size_t)z * 8 + sc) * 4096;
  #pragma unroll
  for (int nn = 0; nn < 4; ++nn) {
    const int n = wave * 4 + nn;
    float4 v = {0.f, 0.f, 0.f, 0.f};
    #pragma unroll
    for (int w = 0; w < 4; ++w) {
      const float4 x = *reinterpret_cast<const float4*>(
          reinterpret_cast<const float*>(&Cs[w][0]) + n * 256 + fbase);
      v.x += x.x; v.y += x.y; v.z += x.z; v.w += x.w;
    }
    *reinterpret_cast<float4*>(Op + n * 256 + fbase) = v;
  }
  if (wave == 0 && lane < 16) {
    const int n = lane;
    const float Mb = fmaxf(fmaxf(wms[0][n], wms[1][n]), fmaxf(wms[2][n], wms[3][n]));
    float Lb = 0.f;
    #pragma unroll
    for (int w = 0; w < 4; ++w) Lb += wls[w][n] * __expf(wms[w][n] - Mb);
    Spart[((size_t)z * 8 + sc) * 32 + n]      = Mb;
    Spart[((size_t)z * 8 + sc) * 32 + 16 + n] = Lb;
  }
}

// ---------------- fused combine + head: out = relu(flat @ W_h^T) ----------------
// Phase A: build flat tile [64 m][256 f] bf16 in LDS directly from Opart/Spart/emb
// (replaces the separate att_combine kernel + flat_h global round-trip).
// Phase B: bf16 MFMA GEMM, A from LDS flat tile, B staged from Wh_h per K-step.
__global__ __launch_bounds__(256) void head_fused(
    const float* __restrict__ Opart, const float* __restrict__ Spart,
    const float* __restrict__ emb, const unsigned short* __restrict__ Wh_h,
    float* __restrict__ out)
{
  __shared__ unsigned short flatT[64 * 264];   // 33.8 KB, CROW-style pad (proven pattern)
  __shared__ unsigned short Bs[64 * 40];
  const int g = blockIdx.z;
  const int n0 = blockIdx.x * 64, m0 = blockIdx.y * 64;
  const int tid = threadIdx.x;
  const int wave = tid >> 6, lane = tid & 63;

  // ---- Phase A: flat[m][f] = bf16(attn/L + emb), 16 rows per wave, all lanes on one row
  for (int rr = 0; rr < 16; ++rr) {
    const int m = wave + 4 * rr;
    const int t = m0 + m;
    const int f0 = lane * 4;
    us4 o = {0, 0, 0, 0};
    if (t < TOTAL) {
      const int b = c_b_of_t[t], n = c_n_of_t[t];
      const int z = (g << 4) + b;
      float M = -3.0e38f;
      #pragma unroll
      for (int sc = 0; sc < 8; ++sc)
        M = fmaxf(M, Spart[((size_t)z * 8 + sc) * 32 + n]);
      float L = 0.f;
      float4 a = {0.f, 0.f, 0.f, 0.f};
      #pragma unroll
      for (int sc = 0; sc < 8; ++sc) {
        const float e = __expf(Spart[((size_t)z * 8 + sc) * 32 + n] - M);
        L += e * Spart[((size_t)z * 8 + sc) * 32 + 16 + n];
        const float4 op = *reinterpret_cast<const float4*>(
            Opart + ((size_t)z * 8 + sc) * 4096 + n * 256 + f0);
        a.x += e * op.x; a.y += e * op.y; a.z += e * op.z; a.w += e * op.w;
      }
      const float4 ev = *reinterpret_cast<const float4*>(
          emb + (size_t)t * INDIM + (g << 8) + f0);
      const float rL = 1.f / L;
      o[0] = f2bf(a.x * rL + ev.x);
      o[1] = f2bf(a.y * rL + ev.y);
      o[2] = f2bf(a.z * rL + ev.z);
      o[3] = f2bf(a.w * rL + ev.w);
    }
    *reinterpret_cast<us4*>(&flatT[m * 264 + f0]) = o;
  }
  __syncthreads();

  // ---- Phase B: GEMM (identical structure to the proven head_mfma, A from flatT)
  const int wm = (wave >> 1) * 32, wn = (wave & 1) * 32;
  const int quad = lane >> 4, lr = lane & 15;
  const int r = tid >> 2, ko = (tid & 3) * 8;
  const unsigned short* Bg = Wh_h + (size_t)g * GF * GF + (size_t)n0 * GF;

  f32x4 acc[2][2];
  #pragma unroll
  for (int i = 0; i < 2; ++i)
    #pragma unroll
    for (int j = 0; j < 2; ++j) acc[i][j] = (f32x4){0.f, 0.f, 0.f, 0.f};

  uint4 rb = *reinterpret_cast<const uint4*>(Bg + (size_t)r * GF + ko);

  for (int kt = 0; kt < 8; ++kt) {
    __syncthreads();
    *reinterpret_cast<uint4*>(&Bs[r * 40 + ko]) = rb;
    __syncthreads();
    if (kt < 7) {
      const int k0 = (kt + 1) * 32;
      rb = *reinterpret_cast<const uint4*>(Bg + (size_t)r * GF + k0 + ko);
    }
    bf16x8 af[2], bfr[2];
    #pragma unroll
    for (int i = 0; i < 2; ++i)
      af[i] = *reinterpret_cast<const bf16x8*>(&flatT[(wm + i * 16 + lr) * 264 + kt * 32 + quad * 8]);
    #pragma unroll
    for (int j = 0; j < 2; ++j)
      bfr[j] = *reinterpret_cast<const bf16x8*>(&Bs[(wn + j * 16 + lr) * 40 + quad * 8]);
    #pragma unroll
    for (int i = 0; i < 2; ++i)
      #pragma unroll
      for (int j = 0; j < 2; ++j)
        acc[i][j] = __builtin_amdgcn_mfma_f32_16x16x32_bf16(af[i], bfr[j], acc[i][j], 0, 0, 0);
  }

  #pragma unroll
  for (int i = 0; i < 2; ++i) {
    #pragma unroll
    for (int reg = 0; reg < 4; ++reg) {
      const int m = m0 + wm + i * 16 + quad * 4 + reg;
      if (m >= TOTAL) continue;
      #pragma unroll
      for (int j = 0; j < 2; ++j) {
        const int n = n0 + wn + j * 16 + lr;
        out[(size_t)m * INDIM + g * GF + n] = fmaxf(acc[i][j][reg], 0.f);
      }
    }
  }
}

extern "C" void kernel_launch(void* const* d_in, const int* in_sizes, int n_in,
                              void* d_out, int out_size, void* d_ws, size_t ws_size,
                              hipStream_t stream) {
  (void)in_sizes; (void)n_in; (void)out_size; (void)ws_size;
  const float* actor = (const float*)d_in[0];
  const float* fmap  = (const float*)d_in[1];
  const float* W_a   = (const float*)d_in[2];
  const float* b_a   = (const float*)d_in[3];
  const float* W_c   = (const float*)d_in[4];
  const float* b_c   = (const float*)d_in[5];
  const float* W_h   = (const float*)d_in[6];
  float* out = (float*)d_out;
  char* ws = (char*)d_ws;

  float* emb             = (float*)(ws);                        // 655,360 B
  unsigned short* emb_h  = (unsigned short*)(ws + 983040);      // 327,680 B
  float* Spart           = (float*)(ws + 1310720);              // 65,536 B
  unsigned short* ctxT   = (unsigned short*)(ws + 1376256);     // 54,525,952 B
  unsigned short* Ah     = (unsigned short*)(ws + 55902208);    // 1,769,472 B
  unsigned short* BhT    = (unsigned short*)(ws + 57671680);    // 43,352,064 B
  float* Opart           = (float*)(ws + 57671680);             // 33,554,432 B, aliases BhT (time-disjoint)
  unsigned short* Wh_h   = (unsigned short*)(ws + 101023744);   // 524,288 B (end 101,548,032)

  // 0) mega-fused front end: emb MFMA + weight packs + wide-read fm transpose
  hipLaunchKernelGGL(prep_all, dim3(6784), dim3(256), 0, stream,
                     actor, W_a, b_a, W_c, W_h, fmap,
                     emb, emb_h, Ah, Wh_h, BhT);

  // 1) ctxT via bf16 MFMA, 128x128 tile, 3-deep ring, counted vmcnt, XCD-bound b
  hipLaunchKernelGGL(ctx_mfma, dim3(1664), dim3(256), 0, stream, Ah, BhT, b_c, ctxT);

  // 2) fused attention (logits + online softmax + PV), s-split 8
  hipLaunchKernelGGL(att_part, dim3(8, 64), dim3(256), 0, stream,
                     ctxT, emb_h, Opart, Spart);

  // 3) fused combine + head: out = relu((attn/L + emb) @ W_h^T)
  hipLaunchKernelGGL(head_fused, dim3(4, 3, 4), dim3(256), 0, stream,
                     Opart, Spart, emb, Wh_h, out);
}

// Round 7
// 267.807 us; speedup vs baseline: 1.0828x; 1.0828x over previous
//
#include <hip/hip_runtime.h>

#define TOTAL   160
#define NMAX    16
#define INDIM   1024
#define DIN     834
#define KPAD    864
#define GF      256
#define SS      1568
#define SPAD    1664   // 13 * 128
#define CROW    264    // ctx LDS row stride in shorts (256 + 8 pad)

__constant__ int c_counts[16] = {6,14,10,8,16,12,9,11,7,13,10,10,8,12,6,8};
__constant__ int c_offs[16]   = {0,6,20,30,38,54,66,75,86,93,106,116,126,134,146,152};
__constant__ int c_t0[8] = {0, 6, 12, 18, 25, 31, 37, 43};   // s-tile ranges (49 tiles of 32)
__constant__ int c_t1[8] = {6, 12, 18, 25, 31, 37, 43, 49};

using bf16x8 = __attribute__((ext_vector_type(8))) short;
using f32x4  = __attribute__((ext_vector_type(4))) float;
using us4    = __attribute__((ext_vector_type(4))) unsigned short;

__device__ inline unsigned short f2bf(float f) {
  union { float f; unsigned u; } v; v.f = f;
  const unsigned u = v.u;
  return (unsigned short)((u + 0x7FFFu + ((u >> 16) & 1u)) >> 16);
}
__device__ inline float bf2f(unsigned short h) {
  union { unsigned u; float f; } v; v.u = ((unsigned)h) << 16; return v.f;
}

// direct global->LDS DMA, 16B per lane. lds dest is wave-uniform base + lane*16B.
__device__ __forceinline__ void gload16(const unsigned short* g, unsigned short* l) {
  __builtin_amdgcn_global_load_lds(
      (const __attribute__((address_space(1))) unsigned int*)(g),
      (__attribute__((address_space(3))) unsigned int*)(l), 16, 0, 0);
}

// ---------------- mega-fused front end (r1 form — empirically best) ----------------
// blocks [0,48): emb bf16 MFMA; [48,3760): Wc/Wh pack; [3760,24928): fm transpose.
__global__ __launch_bounds__(256) void prep_all(
    const float* __restrict__ actor, const float* __restrict__ Wa,
    const float* __restrict__ b_a, const float* __restrict__ Wc,
    const float* __restrict__ Wh, const float* __restrict__ fm,
    float* __restrict__ emb, unsigned short* __restrict__ emb_h,
    unsigned short* __restrict__ Ah, unsigned short* __restrict__ Wh_h,
    unsigned short* __restrict__ BhT)
{
  __shared__ float tile[32][33];
  __shared__ unsigned short As[64 * 40];
  __shared__ unsigned short Bs[64 * 40];
  const int bid = blockIdx.x, tid = threadIdx.x;

  if (bid < 48) {
    // ---- emb: emb[m][n] = sum_k actor[m][k]*Wa[n][k] + b_a[n] ----
    const int n0 = (bid & 15) * 64, m0 = (bid >> 4) * 64;
    const int wave = tid >> 6, lane = tid & 63;
    const int wm = (wave >> 1) * 32, wn = (wave & 1) * 32;
    const int quad = lane >> 4, lr = lane & 15;
    const int r = tid >> 2, ko = (tid & 3) * 8;
    const bool mval = (m0 + r < TOTAL);

    f32x4 acc[2][2];
    #pragma unroll
    for (int i = 0; i < 2; ++i)
      #pragma unroll
      for (int j = 0; j < 2; ++j) acc[i][j] = (f32x4){0.f, 0.f, 0.f, 0.f};

    const float4 zf4 = {0.f, 0.f, 0.f, 0.f};
    float4 ra0, ra1, rb0, rb1;
    ra0 = mval ? *reinterpret_cast<const float4*>(actor + (size_t)(m0 + r) * INDIM + ko) : zf4;
    ra1 = mval ? *reinterpret_cast<const float4*>(actor + (size_t)(m0 + r) * INDIM + ko + 4) : zf4;
    rb0 = *reinterpret_cast<const float4*>(Wa + (size_t)(n0 + r) * INDIM + ko);
    rb1 = *reinterpret_cast<const float4*>(Wa + (size_t)(n0 + r) * INDIM + ko + 4);

    for (int kt = 0; kt < 32; ++kt) {
      __syncthreads();
      {
        us4 a0, a1, b0, b1;
        a0[0]=f2bf(ra0.x); a0[1]=f2bf(ra0.y); a0[2]=f2bf(ra0.z); a0[3]=f2bf(ra0.w);
        a1[0]=f2bf(ra1.x); a1[1]=f2bf(ra1.y); a1[2]=f2bf(ra1.z); a1[3]=f2bf(ra1.w);
        b0[0]=f2bf(rb0.x); b0[1]=f2bf(rb0.y); b0[2]=f2bf(rb0.z); b0[3]=f2bf(rb0.w);
        b1[0]=f2bf(rb1.x); b1[1]=f2bf(rb1.y); b1[2]=f2bf(rb1.z); b1[3]=f2bf(rb1.w);
        *reinterpret_cast<us4*>(&As[r * 40 + ko])     = a0;
        *reinterpret_cast<us4*>(&As[r * 40 + ko + 4]) = a1;
        *reinterpret_cast<us4*>(&Bs[r * 40 + ko])     = b0;
        *reinterpret_cast<us4*>(&Bs[r * 40 + ko + 4]) = b1;
      }
      __syncthreads();
      if (kt < 31) {
        const int k0 = (kt + 1) * 32;
        ra0 = mval ? *reinterpret_cast<const float4*>(actor + (size_t)(m0 + r) * INDIM + k0 + ko) : zf4;
        ra1 = mval ? *reinterpret_cast<const float4*>(actor + (size_t)(m0 + r) * INDIM + k0 + ko + 4) : zf4;
        rb0 = *reinterpret_cast<const float4*>(Wa + (size_t)(n0 + r) * INDIM + k0 + ko);
        rb1 = *reinterpret_cast<const float4*>(Wa + (size_t)(n0 + r) * INDIM + k0 + ko + 4);
      }
      bf16x8 af[2], bfr[2];
      #pragma unroll
      for (int i = 0; i < 2; ++i)
        af[i] = *reinterpret_cast<const bf16x8*>(&As[(wm + i * 16 + lr) * 40 + quad * 8]);
      #pragma unroll
      for (int j = 0; j < 2; ++j)
        bfr[j] = *reinterpret_cast<const bf16x8*>(&Bs[(wn + j * 16 + lr) * 40 + quad * 8]);
      #pragma unroll
      for (int i = 0; i < 2; ++i)
        #pragma unroll
        for (int j = 0; j < 2; ++j)
          acc[i][j] = __builtin_amdgcn_mfma_f32_16x16x32_bf16(af[i], bfr[j], acc[i][j], 0, 0, 0);
    }

    #pragma unroll
    for (int i = 0; i < 2; ++i) {
      #pragma unroll
      for (int reg = 0; reg < 4; ++reg) {
        const int m = m0 + wm + i * 16 + quad * 4 + reg;
        if (m >= TOTAL) continue;
        #pragma unroll
        for (int j = 0; j < 2; ++j) {
          const int n = n0 + wn + j * 16 + lr;
          const float v = acc[i][j][reg] + b_a[n];
          emb[(size_t)m * INDIM + n] = v;
          emb_h[(size_t)m * INDIM + n] = f2bf(v);
        }
      }
    }
  } else if (bid < 3760) {
    const int pb = bid - 48;
    if (pb < 3456) {
      const int idx = pb * 256 + tid;
      const int k = idx % KPAD, gm = idx / KPAD;
      Ah[idx] = (k < DIN) ? f2bf(Wc[gm * DIN + k]) : (unsigned short)0;
    } else {
      const int i = (pb - 3456) * 256 + tid;
      const float4 v = reinterpret_cast<const float4*>(Wh)[i];
      us4 o; o[0] = f2bf(v.x); o[1] = f2bf(v.y); o[2] = f2bf(v.z); o[3] = f2bf(v.w);
      reinterpret_cast<us4*>(Wh_h)[i] = o;
    }
  } else {
    // ---- fm [16][834][1568] fp32 -> BhT [16][1568][864] bf16 ----
    const int fb = bid - 3760;
    const int sx = fb % 49, ky = (fb / 49) % 27, b = fb / (49 * 27);
    const int k0 = ky * 32, s0 = sx * 32;
    const int tx = tid & 31, ty = tid >> 5;
    const float* src = fm + (size_t)b * DIN * SS;
    #pragma unroll
    for (int r = 0; r < 4; ++r) {
      const int k = k0 + ty + r * 8;
      tile[ty + r * 8][tx] = (k < DIN) ? src[(size_t)k * SS + s0 + tx] : 0.f;
    }
    __syncthreads();
    unsigned short* dst = BhT + (size_t)b * SS * KPAD;
    #pragma unroll
    for (int r = 0; r < 4; ++r) {
      const int s = s0 + ty + r * 8;
      dst[(size_t)s * KPAD + k0 + tx] = f2bf(tile[tx][ty + r * 8]);
    }
  }
}

// ---------------- ctx GEMM v4: 128x128 tile, 4-deep ring, ONE barrier per K-step ----------------
// Ring depth 4: refill target buf (k+3)&3 == (k-1)&3, whose readers finished before
// this step's barrier (their ds_read results were consumed by MFMA(k-1) pre-barrier).
// -> the v3 second barrier is provably unnecessary; 27 barriers instead of 54.
// vmcnt retirement is in-order, so vmcnt(8) still == "tile k fully landed" (3 issues
// of 4 loads outstanding). setprio(1) around MFMA cluster (T5; 8 waves/CU role-split).
__global__ __launch_bounds__(256, 2) void ctx_mfma(const unsigned short* __restrict__ Ah,
                                                   const unsigned short* __restrict__ BhT,
                                                   const float* __restrict__ b_c,
                                                   unsigned short* __restrict__ ctxT) {
  __shared__ unsigned short ABuf[4][2][4096];   // [ring][A|B][8KB] = 64 KiB -> 2 blocks/CU
  const int lin  = blockIdx.x;
  const int xcd  = lin & 7;
  const int slot = lin >> 3;                    // 0..207
  const int bloc = (slot >= 104) ? 1 : 0;
  const int within = slot - bloc * 104;         // 0..103
  const int b  = xcd * 2 + bloc;
  const int mt = within % 13;
  const int gn = within / 13;                   // 0..7
  const int g  = gn & 3;
  const int n0 = (gn >> 2) * 128;
  const int m0 = mt * 128;
  const int zout = (g << 4) + b;

  const int tid = threadIdx.x;
  const int w = tid >> 6, lane = tid & 63;
  const int wm = (w >> 1) * 64, wn = (w & 1) * 64;
  const int quad = lane >> 4, lr = lane & 15;

  const unsigned short* Ag = BhT + (size_t)b * SS * KPAD + (size_t)m0 * KPAD;
  const unsigned short* Bg = Ah + (size_t)g * 256 * KPAD + (size_t)n0 * KPAD;

  // DMA source map: linear dest byte o in the 8KB tile -> swizzled (row, k-chunk).
  // 128B line l holds rows {2l, 2l+1} as 8 granules of 16B, stored granule gs = gg ^ (l&7).
  int rS[2], kS[2];
  #pragma unroll
  for (int p = 0; p < 2; ++p) {
    const int o    = p * 4096 + w * 1024 + lane * 16;
    const int line = o >> 7;
    const int gs   = (o >> 4) & 7;
    const int gg   = gs ^ (line & 7);
    rS[p] = line * 2 + (gg >> 2);
    kS[p] = (gg & 3) * 8;                       // shorts
  }

  // ds_read offsets (shorts): fragment (row r, k-quad) -> swizzled granule slot
  int offA[4], offB[4];
  #pragma unroll
  for (int i = 0; i < 4; ++i) {
    const int r = wm + i * 16 + lr;
    const int line = r >> 1;
    const int gs = ((r & 1) * 4 + quad) ^ (line & 7);
    offA[i] = line * 64 + gs * 8;
  }
  #pragma unroll
  for (int j = 0; j < 4; ++j) {
    const int r = wn + j * 16 + lr;
    const int line = r >> 1;
    const int gs = ((r & 1) * 4 + quad) ^ (line & 7);
    offB[j] = line * 64 + gs * 8;
  }

  f32x4 acc[4][4];
  #pragma unroll
  for (int i = 0; i < 4; ++i)
    #pragma unroll
    for (int j = 0; j < 4; ++j) acc[i][j] = (f32x4){0.f, 0.f, 0.f, 0.f};

#define CTX_ISSUE(KT, BUF) {                                                          \
    _Pragma("unroll")                                                                 \
    for (int p = 0; p < 2; ++p) {                                                     \
      gload16(Ag + (size_t)rS[p] * KPAD + (KT) * 32 + kS[p],                          \
              &ABuf[BUF][0][p * 2048 + w * 512]);                                     \
      gload16(Bg + (size_t)rS[p] * KPAD + (KT) * 32 + kS[p],                          \
              &ABuf[BUF][1][p * 2048 + w * 512]);                                     \
    } }

#define CTX_BODY(KT, WAITSTR, DOISSUE) {                                              \
    asm volatile(WAITSTR ::: "memory");        /* tile KT landed (in-order vmcnt)  */ \
    __builtin_amdgcn_s_barrier();              /* all waves: KT landed, KT-1 read  */ \
    if (DOISSUE) CTX_ISSUE((KT) + 3, ((KT) + 3) & 3);  /* refill buf (KT-1)&3 */      \
    bf16x8 af[4], bv[4];                                                              \
    _Pragma("unroll")                                                                 \
    for (int j = 0; j < 4; ++j)                                                       \
      bv[j] = *reinterpret_cast<const bf16x8*>(&ABuf[(KT) & 3][1][offB[j]]);          \
    _Pragma("unroll")                                                                 \
    for (int i = 0; i < 4; ++i)                                                       \
      af[i] = *reinterpret_cast<const bf16x8*>(&ABuf[(KT) & 3][0][offA[i]]);          \
    asm volatile("s_waitcnt lgkmcnt(0)" ::: "memory");                                \
    __builtin_amdgcn_sched_barrier(0);                                                \
    __builtin_amdgcn_s_setprio(1);                                                    \
    _Pragma("unroll")                                                                 \
    for (int i = 0; i < 4; ++i)                                                       \
      _Pragma("unroll")                                                               \
      for (int j = 0; j < 4; ++j)                                                     \
        acc[i][j] = __builtin_amdgcn_mfma_f32_16x16x32_bf16(af[i], bv[j], acc[i][j], 0, 0, 0); \
    __builtin_amdgcn_s_setprio(0);                                                    \
  }

  // prologue: 3 K-tiles in flight (12 vmem ops/wave); buf3 free for step-0 refill
  CTX_ISSUE(0, 0);
  CTX_ISSUE(1, 1);
  CTX_ISSUE(2, 2);

  for (int kt = 0; kt < 24; kt += 4) {
    CTX_BODY(kt,     "s_waitcnt vmcnt(8)", 1);
    CTX_BODY(kt + 1, "s_waitcnt vmcnt(8)", 1);
    CTX_BODY(kt + 2, "s_waitcnt vmcnt(8)", 1);
    CTX_BODY(kt + 3, "s_waitcnt vmcnt(8)", 1);
  }
  CTX_BODY(24, "s_waitcnt vmcnt(8)", 0);
  CTX_BODY(25, "s_waitcnt vmcnt(4)", 0);
  CTX_BODY(26, "s_waitcnt vmcnt(0)", 0);

#undef CTX_BODY
#undef CTX_ISSUE

  // C-write: j innermost -> each 128B line completed by 4 consecutive stores (proven).
  unsigned short* Cz = ctxT + (size_t)zout * SPAD * GF;
  const float* bias = b_c + g * GF;
  float bvj[4];
  #pragma unroll
  for (int j = 0; j < 4; ++j) bvj[j] = bias[n0 + wn + j * 16 + lr];
  #pragma unroll
  for (int i = 0; i < 4; ++i) {
    #pragma unroll
    for (int reg = 0; reg < 4; ++reg) {
      const int m = m0 + wm + i * 16 + quad * 4 + reg;
      #pragma unroll
      for (int j = 0; j < 4; ++j) {
        Cz[(size_t)m * GF + n0 + wn + j * 16 + lr] = f2bf(acc[i][j][reg] + bvj[j]);
      }
    }
  }
}

// ---------------- fused attention (r1 form — empirically best) ----------------
__global__ __launch_bounds__(256) void att_part(
    const unsigned short* __restrict__ ctxT,
    const unsigned short* __restrict__ emb_h,
    float* __restrict__ Opart,     // [64*8][16][256]
    float* __restrict__ Spart)     // [64*8][32]: 16 M then 16 L
{
  __shared__ unsigned short Cs[4][32 * CROW];
  __shared__ float Ps[4][32][20];
  __shared__ float walpha[4][16];
  __shared__ float wms[4][16], wls[4][16];
  const int sc = blockIdx.x, z = blockIdx.y;
  const int g = z >> 4, b = z & 15;
  const int count = c_counts[b], off = c_offs[b];
  const int t0 = c_t0[sc], t1 = c_t1[sc];
  const int tid = threadIdx.x, wave = tid >> 6, lane = tid & 63;
  const int quad = lane >> 4, lr = lane & 15;
  const unsigned short* Az = ctxT + (size_t)z * SPAD * GF;
  const bool bvalid = (lr < count);
  const unsigned short* Brow = emb_h + (size_t)(off + (bvalid ? lr : 0)) * INDIM + (g << 8);
  unsigned short* myC = &Cs[wave][0];
  const int fbase = quad * 64 + lr * 4;
  const bf16x8 zero8 = (bf16x8)(short)0;

  float O[16][4];
  #pragma unroll
  for (int n = 0; n < 16; ++n)
    #pragma unroll
    for (int j = 0; j < 4; ++j) O[n][j] = 0.f;
  float m_run = -3.0e38f, l_run = 0.f;

  for (int t = t0 + wave; t < t1; t += 4) {
    const int s0 = t * 32;
    #pragma unroll
    for (int q = 0; q < 16; ++q) {
      const int row = 2 * q + (lane >> 5);
      const int col = (lane & 31) * 8;
      const uint4 v = *reinterpret_cast<const uint4*>(Az + (size_t)(s0 + row) * GF + col);
      *reinterpret_cast<uint4*>(&myC[row * CROW + col]) = v;
    }
    f32x4 acc[2] = {(f32x4){0.f,0.f,0.f,0.f}, (f32x4){0.f,0.f,0.f,0.f}};
    #pragma unroll
    for (int kk = 0; kk < 8; ++kk) {
      const int f = kk * 32 + quad * 8;
      bf16x8 bv8 = *reinterpret_cast<const bf16x8*>(Brow + f);
      if (!bvalid) bv8 = zero8;
      #pragma unroll
      for (int i = 0; i < 2; ++i) {
        const bf16x8 av8 = *reinterpret_cast<const bf16x8*>(&myC[(i * 16 + lr) * CROW + f]);
        acc[i] = __builtin_amdgcn_mfma_f32_16x16x32_bf16(av8, bv8, acc[i], 0, 0, 0);
      }
    }
    float mx = acc[0][0];
    #pragma unroll
    for (int i = 0; i < 2; ++i)
      #pragma unroll
      for (int r = 0; r < 4; ++r) mx = fmaxf(mx, acc[i][r]);
    float lsum = 0.f;
    #pragma unroll
    for (int i = 0; i < 2; ++i)
      #pragma unroll
      for (int r = 0; r < 4; ++r) lsum += __expf(acc[i][r] - mx);
    #pragma unroll
    for (int d = 16; d < 64; d <<= 1) {
      const float om = __shfl_xor(mx, d, 64);
      const float ol = __shfl_xor(lsum, d, 64);
      const float M = fmaxf(mx, om);
      lsum = lsum * __expf(mx - M) + ol * __expf(om - M);
      mx = M;
    }
    const float m_new = fmaxf(m_run, mx);
    const float alpha = __expf(m_run - m_new);
    const float beta  = __expf(mx - m_new);
    l_run = alpha * l_run + beta * lsum;
    m_run = m_new;
    if (lane < 16) walpha[wave][lane] = alpha;
    #pragma unroll
    for (int i = 0; i < 2; ++i)
      #pragma unroll
      for (int r = 0; r < 4; ++r) {
        const int sl = i * 16 + quad * 4 + r;
        Ps[wave][sl][lr] = beta * __expf(acc[i][r] - mx);
      }
    float av[16];
    {
      const float4 a0 = *reinterpret_cast<const float4*>(&walpha[wave][0]);
      const float4 a1 = *reinterpret_cast<const float4*>(&walpha[wave][4]);
      const float4 a2 = *reinterpret_cast<const float4*>(&walpha[wave][8]);
      const float4 a3 = *reinterpret_cast<const float4*>(&walpha[wave][12]);
      av[0]=a0.x; av[1]=a0.y; av[2]=a0.z; av[3]=a0.w;
      av[4]=a1.x; av[5]=a1.y; av[6]=a1.z; av[7]=a1.w;
      av[8]=a2.x; av[9]=a2.y; av[10]=a2.z; av[11]=a2.w;
      av[12]=a3.x; av[13]=a3.y; av[14]=a3.z; av[15]=a3.w;
    }
    #pragma unroll
    for (int n = 0; n < 16; ++n)
      #pragma unroll
      for (int j = 0; j < 4; ++j) O[n][j] *= av[n];
    for (int s = 0; s < 32; ++s) {
      const float4 p0 = *reinterpret_cast<const float4*>(&Ps[wave][s][0]);
      const float4 p1 = *reinterpret_cast<const float4*>(&Ps[wave][s][4]);
      const float4 p2 = *reinterpret_cast<const float4*>(&Ps[wave][s][8]);
      const float4 p3 = *reinterpret_cast<const float4*>(&Ps[wave][s][12]);
      const us4 cv = *reinterpret_cast<const us4*>(&myC[s * CROW + fbase]);
      const float c0 = bf2f(cv[0]), c1 = bf2f(cv[1]), c2 = bf2f(cv[2]), c3 = bf2f(cv[3]);
      const float pn[16] = {p0.x,p0.y,p0.z,p0.w, p1.x,p1.y,p1.z,p1.w,
                            p2.x,p2.y,p2.z,p2.w, p3.x,p3.y,p3.z,p3.w};
      #pragma unroll
      for (int n = 0; n < 16; ++n) {
        O[n][0] = fmaf(pn[n], c0, O[n][0]);
        O[n][1] = fmaf(pn[n], c1, O[n][1]);
        O[n][2] = fmaf(pn[n], c2, O[n][2]);
        O[n][3] = fmaf(pn[n], c3, O[n][3]);
      }
    }
  }

  if (lane < 16) { wms[wave][lane] = m_run; wls[wave][lane] = l_run; }
  __syncthreads();
  float* Ob = reinterpret_cast<float*>(&Cs[wave][0]);
  #pragma unroll
  for (int n = 0; n < 16; ++n) {
    const float Mb = fmaxf(fmaxf(wms[0][n], wms[1][n]), fmaxf(wms[2][n], wms[3][n]));
    const float e = __expf(wms[wave][n] - Mb);
    #pragma unroll
    for (int j = 0; j < 4; ++j) Ob[n * 256 + fbase + j] = O[n][j] * e;
  }
  __syncthreads();
  float* Op = Opart + ((size_t)z * 8 + sc) * 4096;
  #pragma unroll
  for (int nn = 0; nn < 4; ++nn) {
    const int n = wave * 4 + nn;
    float4 v = {0.f, 0.f, 0.f, 0.f};
    #pragma unroll
    for (int w = 0; w < 4; ++w) {
      const float4 x = *reinterpret_cast<const float4*>(
          reinterpret_cast<const float*>(&Cs[w][0]) + n * 256 + fbase);
      v.x += x.x; v.y += x.y; v.z += x.z; v.w += x.w;
    }
    *reinterpret_cast<float4*>(Op + n * 256 + fbase) = v;
  }
  if (wave == 0 && lane < 16) {
    const int n = lane;
    const float Mb = fmaxf(fmaxf(wms[0][n], wms[1][n]), fmaxf(wms[2][n], wms[3][n]));
    float Lb = 0.f;
    #pragma unroll
    for (int w = 0; w < 4; ++w) Lb += wls[w][n] * __expf(wms[w][n] - Mb);
    Spart[((size_t)z * 8 + sc) * 32 + n]      = Mb;
    Spart[((size_t)z * 8 + sc) * 32 + 16 + n] = Lb;
  }
}

// combine 8 s-chunk partials -> flat_h = bf16(attn + emb). grid (64 z, 16 n).
__global__ __launch_bounds__(256) void att_combine(
    const float* __restrict__ Opart, const float* __restrict__ Spart,
    const float* __restrict__ emb, unsigned short* __restrict__ flat_h) {
  const int z = blockIdx.x, n = blockIdx.y;
  const int g = z >> 4, b = z & 15;
  const int count = c_counts[b], off = c_offs[b];
  if (n >= count) return;
  const int f = threadIdx.x;
  float M = -3.0e38f;
  #pragma unroll
  for (int sc = 0; sc < 8; ++sc)
    M = fmaxf(M, Spart[((size_t)z * 8 + sc) * 32 + n]);
  float L = 0.f, acc = 0.f;
  #pragma unroll
  for (int sc = 0; sc < 8; ++sc) {
    const float e = __expf(Spart[((size_t)z * 8 + sc) * 32 + n] - M);
    L += e * Spart[((size_t)z * 8 + sc) * 32 + 16 + n];
    acc += e * Opart[((size_t)z * 8 + sc) * 4096 + n * 256 + f];
  }
  const int t = off + n;
  const int col = (g << 8) + f;
  flat_h[t * INDIM + col] = f2bf(acc / L + emb[t * INDIM + col]);
}

// ---------------- head: bf16 MFMA, out = relu(flat_h @ W_h^T) ----------------
__global__ __launch_bounds__(256) void head_mfma(const unsigned short* __restrict__ flat_h,
                                                 const unsigned short* __restrict__ Wh_h,
                                                 float* __restrict__ out) {
  __shared__ unsigned short As[64 * 40];
  __shared__ unsigned short Bs[64 * 40];
  const int g = blockIdx.z;
  const int n0 = blockIdx.x * 64, m0 = blockIdx.y * 64;
  const int tid = threadIdx.x;
  const int wave = tid >> 6, lane = tid & 63;
  const int wm = (wave >> 1) * 32, wn = (wave & 1) * 32;
  const int quad = lane >> 4, lr = lane & 15;
  const int r = tid >> 2, ko = (tid & 3) * 8;

  const unsigned short* Ag = flat_h + (size_t)m0 * INDIM + g * GF;
  const unsigned short* Bg = Wh_h + (size_t)g * GF * GF + (size_t)n0 * GF;

  f32x4 acc[2][2];
  #pragma unroll
  for (int i = 0; i < 2; ++i)
    #pragma unroll
    for (int j = 0; j < 2; ++j) acc[i][j] = (f32x4){0.f, 0.f, 0.f, 0.f};

  const uint4 zero4 = {0u, 0u, 0u, 0u};
  uint4 ra, rb;
  ra = (m0 + r < TOTAL) ? *reinterpret_cast<const uint4*>(Ag + (size_t)r * INDIM + ko) : zero4;
  rb = *reinterpret_cast<const uint4*>(Bg + (size_t)r * GF + ko);

  for (int kt = 0; kt < 8; ++kt) {
    __syncthreads();
    *reinterpret_cast<uint4*>(&As[r * 40 + ko]) = ra;
    *reinterpret_cast<uint4*>(&Bs[r * 40 + ko]) = rb;
    __syncthreads();
    if (kt < 7) {
      const int k0 = (kt + 1) * 32;
      ra = (m0 + r < TOTAL) ? *reinterpret_cast<const uint4*>(Ag + (size_t)r * INDIM + k0 + ko) : zero4;
      rb = *reinterpret_cast<const uint4*>(Bg + (size_t)r * GF + k0 + ko);
    }
    bf16x8 af[2], bfr[2];
    #pragma unroll
    for (int i = 0; i < 2; ++i)
      af[i] = *reinterpret_cast<const bf16x8*>(&As[(wm + i * 16 + lr) * 40 + quad * 8]);
    #pragma unroll
    for (int j = 0; j < 2; ++j)
      bfr[j] = *reinterpret_cast<const bf16x8*>(&Bs[(wn + j * 16 + lr) * 40 + quad * 8]);
    #pragma unroll
    for (int i = 0; i < 2; ++i)
      #pragma unroll
      for (int j = 0; j < 2; ++j)
        acc[i][j] = __builtin_amdgcn_mfma_f32_16x16x32_bf16(af[i], bfr[j], acc[i][j], 0, 0, 0);
  }

  #pragma unroll
  for (int i = 0; i < 2; ++i) {
    #pragma unroll
    for (int reg = 0; reg < 4; ++reg) {
      const int m = m0 + wm + i * 16 + quad * 4 + reg;
      if (m >= TOTAL) continue;
      #pragma unroll
      for (int j = 0; j < 2; ++j) {
        const int n = n0 + wn + j * 16 + lr;
        out[(size_t)m * INDIM + g * GF + n] = fmaxf(acc[i][j][reg], 0.f);
      }
    }
  }
}

extern "C" void kernel_launch(void* const* d_in, const int* in_sizes, int n_in,
                              void* d_out, int out_size, void* d_ws, size_t ws_size,
                              hipStream_t stream) {
  (void)in_sizes; (void)n_in; (void)out_size; (void)ws_size;
  const float* actor = (const float*)d_in[0];
  const float* fmap  = (const float*)d_in[1];
  const float* W_a   = (const float*)d_in[2];
  const float* b_a   = (const float*)d_in[3];
  const float* W_c   = (const float*)d_in[4];
  const float* b_c   = (const float*)d_in[5];
  const float* W_h   = (const float*)d_in[6];
  float* out = (float*)d_out;
  char* ws = (char*)d_ws;

  float* emb             = (float*)(ws);                        // 655,360 B
  unsigned short* flat_h = (unsigned short*)(ws + 655360);      // 327,680 B
  unsigned short* emb_h  = (unsigned short*)(ws + 983040);      // 327,680 B
  float* Spart           = (float*)(ws + 1310720);              // 65,536 B
  unsigned short* ctxT   = (unsigned short*)(ws + 1376256);     // 54,525,952 B
  unsigned short* Ah     = (unsigned short*)(ws + 55902208);    // 1,769,472 B
  unsigned short* BhT    = (unsigned short*)(ws + 57671680);    // 43,352,064 B
  float* Opart           = (float*)(ws + 57671680);             // 33,554,432 B, aliases BhT (time-disjoint)
  unsigned short* Wh_h   = (unsigned short*)(ws + 101023744);   // 524,288 B (end 101,548,032)

  // 0) mega-fused front end: emb MFMA + weight packs + fm transpose (r1 form)
  hipLaunchKernelGGL(prep_all, dim3(24928), dim3(256), 0, stream,
                     actor, W_a, b_a, W_c, W_h, fmap,
                     emb, emb_h, Ah, Wh_h, BhT);

  // 1) ctxT via bf16 MFMA, 128x128 tile, 4-deep ring, 1 barrier/K-step, XCD-bound b
  hipLaunchKernelGGL(ctx_mfma, dim3(1664), dim3(256), 0, stream, Ah, BhT, b_c, ctxT);

  // 2) fused attention (logits + online softmax + PV), s-split 8 (r1 form)
  hipLaunchKernelGGL(att_part, dim3(8, 64), dim3(256), 0, stream,
                     ctxT, emb_h, Opart, Spart);

  // 3) combine partials -> flat_h = bf16(attn + emb)
  hipLaunchKernelGGL(att_combine, dim3(64, 16), dim3(256), 0, stream,
                     Opart, Spart, emb, flat_h);

  // 4) out = relu(flat_h @ W_h^T)
  hipLaunchKernelGGL(head_mfma, dim3(4, 3, 4), dim3(256), 0, stream,
                     flat_h, Wh_h, out);
}

// Round 8
// 263.740 us; speedup vs baseline: 1.0995x; 1.0154x over previous
//
#include <hip/hip_runtime.h>

#define TOTAL   160
#define NMAX    16
#define INDIM   1024
#define DIN     834
#define KPAD    864
#define GF      256
#define SS      1568
#define SPAD    1664   // 13 * 128
#define CROW    264    // ctx LDS row stride in shorts (256 + 8 pad)

__constant__ int c_counts[16] = {6,14,10,8,16,12,9,11,7,13,10,10,8,12,6,8};
__constant__ int c_offs[16]   = {0,6,20,30,38,54,66,75,86,93,106,116,126,134,146,152};
__constant__ int c_t0[8] = {0, 6, 12, 18, 25, 31, 37, 43};   // s-tile ranges (49 tiles of 32)
__constant__ int c_t1[8] = {6, 12, 18, 25, 31, 37, 43, 49};

using bf16x8 = __attribute__((ext_vector_type(8))) short;
using f32x4  = __attribute__((ext_vector_type(4))) float;
using us4    = __attribute__((ext_vector_type(4))) unsigned short;

__device__ inline unsigned short f2bf(float f) {
  union { float f; unsigned u; } v; v.f = f;
  const unsigned u = v.u;
  return (unsigned short)((u + 0x7FFFu + ((u >> 16) & 1u)) >> 16);
}
__device__ inline float bf2f(unsigned short h) {
  union { unsigned u; float f; } v; v.u = ((unsigned)h) << 16; return v.f;
}

// direct global->LDS DMA, 16B per lane. lds dest is wave-uniform base + lane*16B.
__device__ __forceinline__ void gload16(const unsigned short* g, unsigned short* l) {
  __builtin_amdgcn_global_load_lds(
      (const __attribute__((address_space(1))) unsigned int*)(g),
      (__attribute__((address_space(3))) unsigned int*)(l), 16, 0, 0);
}

// ---------------- mega-fused front end (r1 form — empirically best) ----------------
// blocks [0,48): emb bf16 MFMA; [48,3760): Wc/Wh pack; [3760,24928): fm transpose.
__global__ __launch_bounds__(256) void prep_all(
    const float* __restrict__ actor, const float* __restrict__ Wa,
    const float* __restrict__ b_a, const float* __restrict__ Wc,
    const float* __restrict__ Wh, const float* __restrict__ fm,
    float* __restrict__ emb, unsigned short* __restrict__ emb_h,
    unsigned short* __restrict__ Ah, unsigned short* __restrict__ Wh_h,
    unsigned short* __restrict__ BhT)
{
  __shared__ float tile[32][33];
  __shared__ unsigned short As[64 * 40];
  __shared__ unsigned short Bs[64 * 40];
  const int bid = blockIdx.x, tid = threadIdx.x;

  if (bid < 48) {
    // ---- emb: emb[m][n] = sum_k actor[m][k]*Wa[n][k] + b_a[n] ----
    const int n0 = (bid & 15) * 64, m0 = (bid >> 4) * 64;
    const int wave = tid >> 6, lane = tid & 63;
    const int wm = (wave >> 1) * 32, wn = (wave & 1) * 32;
    const int quad = lane >> 4, lr = lane & 15;
    const int r = tid >> 2, ko = (tid & 3) * 8;
    const bool mval = (m0 + r < TOTAL);

    f32x4 acc[2][2];
    #pragma unroll
    for (int i = 0; i < 2; ++i)
      #pragma unroll
      for (int j = 0; j < 2; ++j) acc[i][j] = (f32x4){0.f, 0.f, 0.f, 0.f};

    const float4 zf4 = {0.f, 0.f, 0.f, 0.f};
    float4 ra0, ra1, rb0, rb1;
    ra0 = mval ? *reinterpret_cast<const float4*>(actor + (size_t)(m0 + r) * INDIM + ko) : zf4;
    ra1 = mval ? *reinterpret_cast<const float4*>(actor + (size_t)(m0 + r) * INDIM + ko + 4) : zf4;
    rb0 = *reinterpret_cast<const float4*>(Wa + (size_t)(n0 + r) * INDIM + ko);
    rb1 = *reinterpret_cast<const float4*>(Wa + (size_t)(n0 + r) * INDIM + ko + 4);

    for (int kt = 0; kt < 32; ++kt) {
      __syncthreads();
      {
        us4 a0, a1, b0, b1;
        a0[0]=f2bf(ra0.x); a0[1]=f2bf(ra0.y); a0[2]=f2bf(ra0.z); a0[3]=f2bf(ra0.w);
        a1[0]=f2bf(ra1.x); a1[1]=f2bf(ra1.y); a1[2]=f2bf(ra1.z); a1[3]=f2bf(ra1.w);
        b0[0]=f2bf(rb0.x); b0[1]=f2bf(rb0.y); b0[2]=f2bf(rb0.z); b0[3]=f2bf(rb0.w);
        b1[0]=f2bf(rb1.x); b1[1]=f2bf(rb1.y); b1[2]=f2bf(rb1.z); b1[3]=f2bf(rb1.w);
        *reinterpret_cast<us4*>(&As[r * 40 + ko])     = a0;
        *reinterpret_cast<us4*>(&As[r * 40 + ko + 4]) = a1;
        *reinterpret_cast<us4*>(&Bs[r * 40 + ko])     = b0;
        *reinterpret_cast<us4*>(&Bs[r * 40 + ko + 4]) = b1;
      }
      __syncthreads();
      if (kt < 31) {
        const int k0 = (kt + 1) * 32;
        ra0 = mval ? *reinterpret_cast<const float4*>(actor + (size_t)(m0 + r) * INDIM + k0 + ko) : zf4;
        ra1 = mval ? *reinterpret_cast<const float4*>(actor + (size_t)(m0 + r) * INDIM + k0 + ko + 4) : zf4;
        rb0 = *reinterpret_cast<const float4*>(Wa + (size_t)(n0 + r) * INDIM + k0 + ko);
        rb1 = *reinterpret_cast<const float4*>(Wa + (size_t)(n0 + r) * INDIM + k0 + ko + 4);
      }
      bf16x8 af[2], bfr[2];
      #pragma unroll
      for (int i = 0; i < 2; ++i)
        af[i] = *reinterpret_cast<const bf16x8*>(&As[(wm + i * 16 + lr) * 40 + quad * 8]);
      #pragma unroll
      for (int j = 0; j < 2; ++j)
        bfr[j] = *reinterpret_cast<const bf16x8*>(&Bs[(wn + j * 16 + lr) * 40 + quad * 8]);
      #pragma unroll
      for (int i = 0; i < 2; ++i)
        #pragma unroll
        for (int j = 0; j < 2; ++j)
          acc[i][j] = __builtin_amdgcn_mfma_f32_16x16x32_bf16(af[i], bfr[j], acc[i][j], 0, 0, 0);
    }

    #pragma unroll
    for (int i = 0; i < 2; ++i) {
      #pragma unroll
      for (int reg = 0; reg < 4; ++reg) {
        const int m = m0 + wm + i * 16 + quad * 4 + reg;
        if (m >= TOTAL) continue;
        #pragma unroll
        for (int j = 0; j < 2; ++j) {
          const int n = n0 + wn + j * 16 + lr;
          const float v = acc[i][j][reg] + b_a[n];
          emb[(size_t)m * INDIM + n] = v;
          emb_h[(size_t)m * INDIM + n] = f2bf(v);
        }
      }
    }
  } else if (bid < 3760) {
    const int pb = bid - 48;
    if (pb < 3456) {
      const int idx = pb * 256 + tid;
      const int k = idx % KPAD, gm = idx / KPAD;
      Ah[idx] = (k < DIN) ? f2bf(Wc[gm * DIN + k]) : (unsigned short)0;
    } else {
      const int i = (pb - 3456) * 256 + tid;
      const float4 v = reinterpret_cast<const float4*>(Wh)[i];
      us4 o; o[0] = f2bf(v.x); o[1] = f2bf(v.y); o[2] = f2bf(v.z); o[3] = f2bf(v.w);
      reinterpret_cast<us4*>(Wh_h)[i] = o;
    }
  } else {
    // ---- fm [16][834][1568] fp32 -> BhT [16][1568][864] bf16 ----
    const int fb = bid - 3760;
    const int sx = fb % 49, ky = (fb / 49) % 27, b = fb / (49 * 27);
    const int k0 = ky * 32, s0 = sx * 32;
    const int tx = tid & 31, ty = tid >> 5;
    const float* src = fm + (size_t)b * DIN * SS;
    #pragma unroll
    for (int r = 0; r < 4; ++r) {
      const int k = k0 + ty + r * 8;
      tile[ty + r * 8][tx] = (k < DIN) ? src[(size_t)k * SS + s0 + tx] : 0.f;
    }
    __syncthreads();
    unsigned short* dst = BhT + (size_t)b * SS * KPAD;
    #pragma unroll
    for (int r = 0; r < 4; ++r) {
      const int s = s0 + ty + r * 8;
      dst[(size_t)s * KPAD + k0 + tx] = f2bf(tile[tx][ty + r * 8]);
    }
  }
}

// ---------------- ctx GEMM v5: v3 structure + A-panel-consecutive slot order ----------------
// v3 (proven 70.0 µs): 128x128 tile, 3-deep gload_lds ring, counted vmcnt, 2 raw
// barriers/K-step, granule-XOR swizzle (0 conflicts), j-innermost C-write.
// NEW: within = mt*8 + gn (was gn*13 + mt) -> the 8 blocks (4g x 2n0) consuming one
// 2.7MB A-panel are CONSECUTIVE slots on their XCD, co-resident -> panel stays L2-hot
// (4MB L2 holds ~1.5 panels; the old 13-slot spread caused ~24MB of HBM re-fetch).
__global__ __launch_bounds__(256, 3) void ctx_mfma(const unsigned short* __restrict__ Ah,
                                                   const unsigned short* __restrict__ BhT,
                                                   const float* __restrict__ b_c,
                                                   unsigned short* __restrict__ ctxT) {
  __shared__ unsigned short ABuf[3][2][4096];   // [ring][A|B][8KB] = 48 KiB -> 3 blocks/CU
  const int lin  = blockIdx.x;
  const int xcd  = lin & 7;
  const int slot = lin >> 3;                    // 0..207
  const int bloc = (slot >= 104) ? 1 : 0;
  const int within = slot - bloc * 104;         // 0..103
  const int b  = xcd * 2 + bloc;
  const int mt = within >> 3;                   // 0..12  (A-panel id — 8 consecutive consumers)
  const int gn = within & 7;                    // 0..7
  const int g  = gn & 3;
  const int n0 = (gn >> 2) * 128;
  const int m0 = mt * 128;
  const int zout = (g << 4) + b;

  const int tid = threadIdx.x;
  const int w = tid >> 6, lane = tid & 63;
  const int wm = (w >> 1) * 64, wn = (w & 1) * 64;
  const int quad = lane >> 4, lr = lane & 15;

  const unsigned short* Ag = BhT + (size_t)b * SS * KPAD + (size_t)m0 * KPAD;
  const unsigned short* Bg = Ah + (size_t)g * 256 * KPAD + (size_t)n0 * KPAD;

  // DMA source map: linear dest byte o in the 8KB tile -> swizzled (row, k-chunk).
  // 128B line l holds rows {2l, 2l+1} as 8 granules of 16B, stored granule gs = gg ^ (l&7).
  int rS[2], kS[2];
  #pragma unroll
  for (int p = 0; p < 2; ++p) {
    const int o    = p * 4096 + w * 1024 + lane * 16;
    const int line = o >> 7;
    const int gs   = (o >> 4) & 7;
    const int gg   = gs ^ (line & 7);
    rS[p] = line * 2 + (gg >> 2);
    kS[p] = (gg & 3) * 8;                       // shorts
  }

  // ds_read offsets (shorts): fragment (row r, k-quad) -> swizzled granule slot
  int offA[4], offB[4];
  #pragma unroll
  for (int i = 0; i < 4; ++i) {
    const int r = wm + i * 16 + lr;
    const int line = r >> 1;
    const int gs = ((r & 1) * 4 + quad) ^ (line & 7);
    offA[i] = line * 64 + gs * 8;
  }
  #pragma unroll
  for (int j = 0; j < 4; ++j) {
    const int r = wn + j * 16 + lr;
    const int line = r >> 1;
    const int gs = ((r & 1) * 4 + quad) ^ (line & 7);
    offB[j] = line * 64 + gs * 8;
  }

  f32x4 acc[4][4];
  #pragma unroll
  for (int i = 0; i < 4; ++i)
    #pragma unroll
    for (int j = 0; j < 4; ++j) acc[i][j] = (f32x4){0.f, 0.f, 0.f, 0.f};

#define CTX_ISSUE(KT, BUF) {                                                          \
    _Pragma("unroll")                                                                 \
    for (int p = 0; p < 2; ++p) {                                                     \
      gload16(Ag + (size_t)rS[p] * KPAD + (KT) * 32 + kS[p],                          \
              &ABuf[BUF][0][p * 2048 + w * 512]);                                     \
      gload16(Bg + (size_t)rS[p] * KPAD + (KT) * 32 + kS[p],                          \
              &ABuf[BUF][1][p * 2048 + w * 512]);                                     \
    } }

#define CTX_BODY(KT, BUF, WAITSTR, DOISSUE) {                                         \
    asm volatile(WAITSTR ::: "memory");                                               \
    __builtin_amdgcn_s_barrier();               /* tile KT fully landed, all waves */ \
    bf16x8 af[4], bv[4];                                                              \
    _Pragma("unroll")                                                                 \
    for (int j = 0; j < 4; ++j)                                                       \
      bv[j] = *reinterpret_cast<const bf16x8*>(&ABuf[BUF][1][offB[j]]);               \
    _Pragma("unroll")                                                                 \
    for (int i = 0; i < 4; ++i)                                                       \
      af[i] = *reinterpret_cast<const bf16x8*>(&ABuf[BUF][0][offA[i]]);               \
    asm volatile("s_waitcnt lgkmcnt(0)" ::: "memory");                                \
    __builtin_amdgcn_sched_barrier(0);                                                \
    __builtin_amdgcn_s_barrier();               /* all reads of BUF complete */       \
    if (DOISSUE) CTX_ISSUE((KT) + 3, BUF);      /* refill just-freed buffer */        \
    _Pragma("unroll")                                                                 \
    for (int i = 0; i < 4; ++i)                                                       \
      _Pragma("unroll")                                                               \
      for (int j = 0; j < 4; ++j)                                                     \
        acc[i][j] = __builtin_amdgcn_mfma_f32_16x16x32_bf16(af[i], bv[j], acc[i][j], 0, 0, 0); \
  }

  // prologue: 3 K-tiles in flight (12 vmem ops/wave)
  CTX_ISSUE(0, 0);
  CTX_ISSUE(1, 1);
  CTX_ISSUE(2, 2);

  for (int kt = 0; kt < 24; kt += 3) {
    CTX_BODY(kt,     0, "s_waitcnt vmcnt(8)", 1);
    CTX_BODY(kt + 1, 1, "s_waitcnt vmcnt(8)", 1);
    CTX_BODY(kt + 2, 2, "s_waitcnt vmcnt(8)", 1);
  }
  CTX_BODY(24, 0, "s_waitcnt vmcnt(8)", 0);
  CTX_BODY(25, 1, "s_waitcnt vmcnt(4)", 0);
  CTX_BODY(26, 2, "s_waitcnt vmcnt(0)", 0);

#undef CTX_BODY
#undef CTX_ISSUE

  // C-write: j innermost -> each 128B line completed by 4 consecutive stores (proven).
  unsigned short* Cz = ctxT + (size_t)zout * SPAD * GF;
  const float* bias = b_c + g * GF;
  float bvj[4];
  #pragma unroll
  for (int j = 0; j < 4; ++j) bvj[j] = bias[n0 + wn + j * 16 + lr];
  #pragma unroll
  for (int i = 0; i < 4; ++i) {
    #pragma unroll
    for (int reg = 0; reg < 4; ++reg) {
      const int m = m0 + wm + i * 16 + quad * 4 + reg;
      #pragma unroll
      for (int j = 0; j < 4; ++j) {
        Cz[(size_t)m * GF + n0 + wn + j * 16 + lr] = f2bf(acc[i][j][reg] + bvj[j]);
      }
    }
  }
}

// ---------------- fused attention (r1 form — empirically best) ----------------
__global__ __launch_bounds__(256) void att_part(
    const unsigned short* __restrict__ ctxT,
    const unsigned short* __restrict__ emb_h,
    float* __restrict__ Opart,     // [64*8][16][256]
    float* __restrict__ Spart)     // [64*8][32]: 16 M then 16 L
{
  __shared__ unsigned short Cs[4][32 * CROW];
  __shared__ float Ps[4][32][20];
  __shared__ float walpha[4][16];
  __shared__ float wms[4][16], wls[4][16];
  const int sc = blockIdx.x, z = blockIdx.y;
  const int g = z >> 4, b = z & 15;
  const int count = c_counts[b], off = c_offs[b];
  const int t0 = c_t0[sc], t1 = c_t1[sc];
  const int tid = threadIdx.x, wave = tid >> 6, lane = tid & 63;
  const int quad = lane >> 4, lr = lane & 15;
  const unsigned short* Az = ctxT + (size_t)z * SPAD * GF;
  const bool bvalid = (lr < count);
  const unsigned short* Brow = emb_h + (size_t)(off + (bvalid ? lr : 0)) * INDIM + (g << 8);
  unsigned short* myC = &Cs[wave][0];
  const int fbase = quad * 64 + lr * 4;
  const bf16x8 zero8 = (bf16x8)(short)0;

  float O[16][4];
  #pragma unroll
  for (int n = 0; n < 16; ++n)
    #pragma unroll
    for (int j = 0; j < 4; ++j) O[n][j] = 0.f;
  float m_run = -3.0e38f, l_run = 0.f;

  for (int t = t0 + wave; t < t1; t += 4) {
    const int s0 = t * 32;
    #pragma unroll
    for (int q = 0; q < 16; ++q) {
      const int row = 2 * q + (lane >> 5);
      const int col = (lane & 31) * 8;
      const uint4 v = *reinterpret_cast<const uint4*>(Az + (size_t)(s0 + row) * GF + col);
      *reinterpret_cast<uint4*>(&myC[row * CROW + col]) = v;
    }
    f32x4 acc[2] = {(f32x4){0.f,0.f,0.f,0.f}, (f32x4){0.f,0.f,0.f,0.f}};
    #pragma unroll
    for (int kk = 0; kk < 8; ++kk) {
      const int f = kk * 32 + quad * 8;
      bf16x8 bv8 = *reinterpret_cast<const bf16x8*>(Brow + f);
      if (!bvalid) bv8 = zero8;
      #pragma unroll
      for (int i = 0; i < 2; ++i) {
        const bf16x8 av8 = *reinterpret_cast<const bf16x8*>(&myC[(i * 16 + lr) * CROW + f]);
        acc[i] = __builtin_amdgcn_mfma_f32_16x16x32_bf16(av8, bv8, acc[i], 0, 0, 0);
      }
    }
    float mx = acc[0][0];
    #pragma unroll
    for (int i = 0; i < 2; ++i)
      #pragma unroll
      for (int r = 0; r < 4; ++r) mx = fmaxf(mx, acc[i][r]);
    float lsum = 0.f;
    #pragma unroll
    for (int i = 0; i < 2; ++i)
      #pragma unroll
      for (int r = 0; r < 4; ++r) lsum += __expf(acc[i][r] - mx);
    #pragma unroll
    for (int d = 16; d < 64; d <<= 1) {
      const float om = __shfl_xor(mx, d, 64);
      const float ol = __shfl_xor(lsum, d, 64);
      const float M = fmaxf(mx, om);
      lsum = lsum * __expf(mx - M) + ol * __expf(om - M);
      mx = M;
    }
    const float m_new = fmaxf(m_run, mx);
    const float alpha = __expf(m_run - m_new);
    const float beta  = __expf(mx - m_new);
    l_run = alpha * l_run + beta * lsum;
    m_run = m_new;
    if (lane < 16) walpha[wave][lane] = alpha;
    #pragma unroll
    for (int i = 0; i < 2; ++i)
      #pragma unroll
      for (int r = 0; r < 4; ++r) {
        const int sl = i * 16 + quad * 4 + r;
        Ps[wave][sl][lr] = beta * __expf(acc[i][r] - mx);
      }
    float av[16];
    {
      const float4 a0 = *reinterpret_cast<const float4*>(&walpha[wave][0]);
      const float4 a1 = *reinterpret_cast<const float4*>(&walpha[wave][4]);
      const float4 a2 = *reinterpret_cast<const float4*>(&walpha[wave][8]);
      const float4 a3 = *reinterpret_cast<const float4*>(&walpha[wave][12]);
      av[0]=a0.x; av[1]=a0.y; av[2]=a0.z; av[3]=a0.w;
      av[4]=a1.x; av[5]=a1.y; av[6]=a1.z; av[7]=a1.w;
      av[8]=a2.x; av[9]=a2.y; av[10]=a2.z; av[11]=a2.w;
      av[12]=a3.x; av[13]=a3.y; av[14]=a3.z; av[15]=a3.w;
    }
    #pragma unroll
    for (int n = 0; n < 16; ++n)
      #pragma unroll
      for (int j = 0; j < 4; ++j) O[n][j] *= av[n];
    for (int s = 0; s < 32; ++s) {
      const float4 p0 = *reinterpret_cast<const float4*>(&Ps[wave][s][0]);
      const float4 p1 = *reinterpret_cast<const float4*>(&Ps[wave][s][4]);
      const float4 p2 = *reinterpret_cast<const float4*>(&Ps[wave][s][8]);
      const float4 p3 = *reinterpret_cast<const float4*>(&Ps[wave][s][12]);
      const us4 cv = *reinterpret_cast<const us4*>(&myC[s * CROW + fbase]);
      const float c0 = bf2f(cv[0]), c1 = bf2f(cv[1]), c2 = bf2f(cv[2]), c3 = bf2f(cv[3]);
      const float pn[16] = {p0.x,p0.y,p0.z,p0.w, p1.x,p1.y,p1.z,p1.w,
                            p2.x,p2.y,p2.z,p2.w, p3.x,p3.y,p3.z,p3.w};
      #pragma unroll
      for (int n = 0; n < 16; ++n) {
        O[n][0] = fmaf(pn[n], c0, O[n][0]);
        O[n][1] = fmaf(pn[n], c1, O[n][1]);
        O[n][2] = fmaf(pn[n], c2, O[n][2]);
        O[n][3] = fmaf(pn[n], c3, O[n][3]);
      }
    }
  }

  if (lane < 16) { wms[wave][lane] = m_run; wls[wave][lane] = l_run; }
  __syncthreads();
  float* Ob = reinterpret_cast<float*>(&Cs[wave][0]);
  #pragma unroll
  for (int n = 0; n < 16; ++n) {
    const float Mb = fmaxf(fmaxf(wms[0][n], wms[1][n]), fmaxf(wms[2][n], wms[3][n]));
    const float e = __expf(wms[wave][n] - Mb);
    #pragma unroll
    for (int j = 0; j < 4; ++j) Ob[n * 256 + fbase + j] = O[n][j] * e;
  }
  __syncthreads();
  float* Op = Opart + ((size_t)z * 8 + sc) * 4096;
  #pragma unroll
  for (int nn = 0; nn < 4; ++nn) {
    const int n = wave * 4 + nn;
    float4 v = {0.f, 0.f, 0.f, 0.f};
    #pragma unroll
    for (int w = 0; w < 4; ++w) {
      const float4 x = *reinterpret_cast<const float4*>(
          reinterpret_cast<const float*>(&Cs[w][0]) + n * 256 + fbase);
      v.x += x.x; v.y += x.y; v.z += x.z; v.w += x.w;
    }
    *reinterpret_cast<float4*>(Op + n * 256 + fbase) = v;
  }
  if (wave == 0 && lane < 16) {
    const int n = lane;
    const float Mb = fmaxf(fmaxf(wms[0][n], wms[1][n]), fmaxf(wms[2][n], wms[3][n]));
    float Lb = 0.f;
    #pragma unroll
    for (int w = 0; w < 4; ++w) Lb += wls[w][n] * __expf(wms[w][n] - Mb);
    Spart[((size_t)z * 8 + sc) * 32 + n]      = Mb;
    Spart[((size_t)z * 8 + sc) * 32 + 16 + n] = Lb;
  }
}

// combine 8 s-chunk partials -> flat_h = bf16(attn + emb). grid (64 z, 16 n).
__global__ __launch_bounds__(256) void att_combine(
    const float* __restrict__ Opart, const float* __restrict__ Spart,
    const float* __restrict__ emb, unsigned short* __restrict__ flat_h) {
  const int z = blockIdx.x, n = blockIdx.y;
  const int g = z >> 4, b = z & 15;
  const int count = c_counts[b], off = c_offs[b];
  if (n >= count) return;
  const int f = threadIdx.x;
  float M = -3.0e38f;
  #pragma unroll
  for (int sc = 0; sc < 8; ++sc)
    M = fmaxf(M, Spart[((size_t)z * 8 + sc) * 32 + n]);
  float L = 0.f, acc = 0.f;
  #pragma unroll
  for (int sc = 0; sc < 8; ++sc) {
    const float e = __expf(Spart[((size_t)z * 8 + sc) * 32 + n] - M);
    L += e * Spart[((size_t)z * 8 + sc) * 32 + 16 + n];
    acc += e * Opart[((size_t)z * 8 + sc) * 4096 + n * 256 + f];
  }
  const int t = off + n;
  const int col = (g << 8) + f;
  flat_h[t * INDIM + col] = f2bf(acc / L + emb[t * INDIM + col]);
}

// ---------------- head: bf16 MFMA, out = relu(flat_h @ W_h^T) ----------------
__global__ __launch_bounds__(256) void head_mfma(const unsigned short* __restrict__ flat_h,
                                                 const unsigned short* __restrict__ Wh_h,
                                                 float* __restrict__ out) {
  __shared__ unsigned short As[64 * 40];
  __shared__ unsigned short Bs[64 * 40];
  const int g = blockIdx.z;
  const int n0 = blockIdx.x * 64, m0 = blockIdx.y * 64;
  const int tid = threadIdx.x;
  const int wave = tid >> 6, lane = tid & 63;
  const int wm = (wave >> 1) * 32, wn = (wave & 1) * 32;
  const int quad = lane >> 4, lr = lane & 15;
  const int r = tid >> 2, ko = (tid & 3) * 8;

  const unsigned short* Ag = flat_h + (size_t)m0 * INDIM + g * GF;
  const unsigned short* Bg = Wh_h + (size_t)g * GF * GF + (size_t)n0 * GF;

  f32x4 acc[2][2];
  #pragma unroll
  for (int i = 0; i < 2; ++i)
    #pragma unroll
    for (int j = 0; j < 2; ++j) acc[i][j] = (f32x4){0.f, 0.f, 0.f, 0.f};

  const uint4 zero4 = {0u, 0u, 0u, 0u};
  uint4 ra, rb;
  ra = (m0 + r < TOTAL) ? *reinterpret_cast<const uint4*>(Ag + (size_t)r * INDIM + ko) : zero4;
  rb = *reinterpret_cast<const uint4*>(Bg + (size_t)r * GF + ko);

  for (int kt = 0; kt < 8; ++kt) {
    __syncthreads();
    *reinterpret_cast<uint4*>(&As[r * 40 + ko]) = ra;
    *reinterpret_cast<uint4*>(&Bs[r * 40 + ko]) = rb;
    __syncthreads();
    if (kt < 7) {
      const int k0 = (kt + 1) * 32;
      ra = (m0 + r < TOTAL) ? *reinterpret_cast<const uint4*>(Ag + (size_t)r * INDIM + k0 + ko) : zero4;
      rb = *reinterpret_cast<const uint4*>(Bg + (size_t)r * GF + k0 + ko);
    }
    bf16x8 af[2], bfr[2];
    #pragma unroll
    for (int i = 0; i < 2; ++i)
      af[i] = *reinterpret_cast<const bf16x8*>(&As[(wm + i * 16 + lr) * 40 + quad * 8]);
    #pragma unroll
    for (int j = 0; j < 2; ++j)
      bfr[j] = *reinterpret_cast<const bf16x8*>(&Bs[(wn + j * 16 + lr) * 40 + quad * 8]);
    #pragma unroll
    for (int i = 0; i < 2; ++i)
      #pragma unroll
      for (int j = 0; j < 2; ++j)
        acc[i][j] = __builtin_amdgcn_mfma_f32_16x16x32_bf16(af[i], bfr[j], acc[i][j], 0, 0, 0);
  }

  #pragma unroll
  for (int i = 0; i < 2; ++i) {
    #pragma unroll
    for (int reg = 0; reg < 4; ++reg) {
      const int m = m0 + wm + i * 16 + quad * 4 + reg;
      if (m >= TOTAL) continue;
      #pragma unroll
      for (int j = 0; j < 2; ++j) {
        const int n = n0 + wn + j * 16 + lr;
        out[(size_t)m * INDIM + g * GF + n] = fmaxf(acc[i][j][reg], 0.f);
      }
    }
  }
}

extern "C" void kernel_launch(void* const* d_in, const int* in_sizes, int n_in,
                              void* d_out, int out_size, void* d_ws, size_t ws_size,
                              hipStream_t stream) {
  (void)in_sizes; (void)n_in; (void)out_size; (void)ws_size;
  const float* actor = (const float*)d_in[0];
  const float* fmap  = (const float*)d_in[1];
  const float* W_a   = (const float*)d_in[2];
  const float* b_a   = (const float*)d_in[3];
  const float* W_c   = (const float*)d_in[4];
  const float* b_c   = (const float*)d_in[5];
  const float* W_h   = (const float*)d_in[6];
  float* out = (float*)d_out;
  char* ws = (char*)d_ws;

  float* emb             = (float*)(ws);                        // 655,360 B
  unsigned short* flat_h = (unsigned short*)(ws + 655360);      // 327,680 B
  unsigned short* emb_h  = (unsigned short*)(ws + 983040);      // 327,680 B
  float* Spart           = (float*)(ws + 1310720);              // 65,536 B
  unsigned short* ctxT   = (unsigned short*)(ws + 1376256);     // 54,525,952 B
  unsigned short* Ah     = (unsigned short*)(ws + 55902208);    // 1,769,472 B
  unsigned short* BhT    = (unsigned short*)(ws + 57671680);    // 43,352,064 B
  float* Opart           = (float*)(ws + 57671680);             // 33,554,432 B, aliases BhT (time-disjoint)
  unsigned short* Wh_h   = (unsigned short*)(ws + 101023744);   // 524,288 B (end 101,548,032)

  // 0) mega-fused front end: emb MFMA + weight packs + fm transpose (r1 form)
  hipLaunchKernelGGL(prep_all, dim3(24928), dim3(256), 0, stream,
                     actor, W_a, b_a, W_c, W_h, fmap,
                     emb, emb_h, Ah, Wh_h, BhT);

  // 1) ctxT via bf16 MFMA, v3 ring + A-panel-consecutive slot order, XCD-bound b
  hipLaunchKernelGGL(ctx_mfma, dim3(1664), dim3(256), 0, stream, Ah, BhT, b_c, ctxT);

  // 2) fused attention (logits + online softmax + PV), s-split 8 (r1 form)
  hipLaunchKernelGGL(att_part, dim3(8, 64), dim3(256), 0, stream,
                     ctxT, emb_h, Opart, Spart);

  // 3) combine partials -> flat_h = bf16(attn + emb)
  hipLaunchKernelGGL(att_combine, dim3(64, 16), dim3(256), 0, stream,
                     Opart, Spart, emb, flat_h);

  // 4) out = relu(flat_h @ W_h^T)
  hipLaunchKernelGGL(head_mfma, dim3(4, 3, 4), dim3(256), 0, stream,
                     flat_h, Wh_h, out);
}

// Round 12
// 260.206 us; speedup vs baseline: 1.1144x; 1.0136x over previous
//
#include <hip/hip_runtime.h>

#define TOTAL   160
#define NMAX    16
#define INDIM   1024
#define DIN     834
#define KPAD    864
#define GF      256
#define SS      1568
#define SPAD    1664   // 13 * 128
#define CROW    264    // ctx LDS row stride in shorts (256 + 8 pad)

__constant__ int c_counts[16] = {6,14,10,8,16,12,9,11,7,13,10,10,8,12,6,8};
__constant__ int c_offs[16]   = {0,6,20,30,38,54,66,75,86,93,106,116,126,134,146,152};
__constant__ int c_t0[8] = {0, 6, 12, 18, 25, 31, 37, 43};   // s-tile ranges (49 tiles of 32)
__constant__ int c_t1[8] = {6, 12, 18, 25, 31, 37, 43, 49};

using bf16x8 = __attribute__((ext_vector_type(8))) short;
using f32x4  = __attribute__((ext_vector_type(4))) float;
using us4    = __attribute__((ext_vector_type(4))) unsigned short;

__device__ inline unsigned short f2bf(float f) {
  union { float f; unsigned u; } v; v.f = f;
  const unsigned u = v.u;
  return (unsigned short)((u + 0x7FFFu + ((u >> 16) & 1u)) >> 16);
}
__device__ inline float bf2f(unsigned short h) {
  union { unsigned u; float f; } v; v.u = ((unsigned)h) << 16; return v.f;
}

// direct global->LDS DMA, 16B per lane. lds dest is wave-uniform base + lane*16B.
__device__ __forceinline__ void gload16(const unsigned short* g, unsigned short* l) {
  __builtin_amdgcn_global_load_lds(
      (const __attribute__((address_space(1))) unsigned int*)(g),
      (__attribute__((address_space(3))) unsigned int*)(l), 16, 0, 0);
}

// ---------------- mega-fused front end (r1 form — empirically best) ----------------
// blocks [0,48): emb bf16 MFMA; [48,3760): Wc/Wh pack; [3760,24928): fm transpose.
__global__ __launch_bounds__(256) void prep_all(
    const float* __restrict__ actor, const float* __restrict__ Wa,
    const float* __restrict__ b_a, const float* __restrict__ Wc,
    const float* __restrict__ Wh, const float* __restrict__ fm,
    float* __restrict__ emb, unsigned short* __restrict__ emb_h,
    unsigned short* __restrict__ Ah, unsigned short* __restrict__ Wh_h,
    unsigned short* __restrict__ BhT)
{
  __shared__ float tile[32][33];
  __shared__ unsigned short As[64 * 40];
  __shared__ unsigned short Bs[64 * 40];
  const int bid = blockIdx.x, tid = threadIdx.x;

  if (bid < 48) {
    // ---- emb: emb[m][n] = sum_k actor[m][k]*Wa[n][k] + b_a[n] ----
    const int n0 = (bid & 15) * 64, m0 = (bid >> 4) * 64;
    const int wave = tid >> 6, lane = tid & 63;
    const int wm = (wave >> 1) * 32, wn = (wave & 1) * 32;
    const int quad = lane >> 4, lr = lane & 15;
    const int r = tid >> 2, ko = (tid & 3) * 8;
    const bool mval = (m0 + r < TOTAL);

    f32x4 acc[2][2];
    #pragma unroll
    for (int i = 0; i < 2; ++i)
      #pragma unroll
      for (int j = 0; j < 2; ++j) acc[i][j] = (f32x4){0.f, 0.f, 0.f, 0.f};

    const float4 zf4 = {0.f, 0.f, 0.f, 0.f};
    float4 ra0, ra1, rb0, rb1;
    ra0 = mval ? *reinterpret_cast<const float4*>(actor + (size_t)(m0 + r) * INDIM + ko) : zf4;
    ra1 = mval ? *reinterpret_cast<const float4*>(actor + (size_t)(m0 + r) * INDIM + ko + 4) : zf4;
    rb0 = *reinterpret_cast<const float4*>(Wa + (size_t)(n0 + r) * INDIM + ko);
    rb1 = *reinterpret_cast<const float4*>(Wa + (size_t)(n0 + r) * INDIM + ko + 4);

    for (int kt = 0; kt < 32; ++kt) {
      __syncthreads();
      {
        us4 a0, a1, b0, b1;
        a0[0]=f2bf(ra0.x); a0[1]=f2bf(ra0.y); a0[2]=f2bf(ra0.z); a0[3]=f2bf(ra0.w);
        a1[0]=f2bf(ra1.x); a1[1]=f2bf(ra1.y); a1[2]=f2bf(ra1.z); a1[3]=f2bf(ra1.w);
        b0[0]=f2bf(rb0.x); b0[1]=f2bf(rb0.y); b0[2]=f2bf(rb0.z); b0[3]=f2bf(rb0.w);
        b1[0]=f2bf(rb1.x); b1[1]=f2bf(rb1.y); b1[2]=f2bf(rb1.z); b1[3]=f2bf(rb1.w);
        *reinterpret_cast<us4*>(&As[r * 40 + ko])     = a0;
        *reinterpret_cast<us4*>(&As[r * 40 + ko + 4]) = a1;
        *reinterpret_cast<us4*>(&Bs[r * 40 + ko])     = b0;
        *reinterpret_cast<us4*>(&Bs[r * 40 + ko + 4]) = b1;
      }
      __syncthreads();
      if (kt < 31) {
        const int k0 = (kt + 1) * 32;
        ra0 = mval ? *reinterpret_cast<const float4*>(actor + (size_t)(m0 + r) * INDIM + k0 + ko) : zf4;
        ra1 = mval ? *reinterpret_cast<const float4*>(actor + (size_t)(m0 + r) * INDIM + k0 + ko + 4) : zf4;
        rb0 = *reinterpret_cast<const float4*>(Wa + (size_t)(n0 + r) * INDIM + k0 + ko);
        rb1 = *reinterpret_cast<const float4*>(Wa + (size_t)(n0 + r) * INDIM + k0 + ko + 4);
      }
      bf16x8 af[2], bfr[2];
      #pragma unroll
      for (int i = 0; i < 2; ++i)
        af[i] = *reinterpret_cast<const bf16x8*>(&As[(wm + i * 16 + lr) * 40 + quad * 8]);
      #pragma unroll
      for (int j = 0; j < 2; ++j)
        bfr[j] = *reinterpret_cast<const bf16x8*>(&Bs[(wn + j * 16 + lr) * 40 + quad * 8]);
      #pragma unroll
      for (int i = 0; i < 2; ++i)
        #pragma unroll
        for (int j = 0; j < 2; ++j)
          acc[i][j] = __builtin_amdgcn_mfma_f32_16x16x32_bf16(af[i], bfr[j], acc[i][j], 0, 0, 0);
    }

    #pragma unroll
    for (int i = 0; i < 2; ++i) {
      #pragma unroll
      for (int reg = 0; reg < 4; ++reg) {
        const int m = m0 + wm + i * 16 + quad * 4 + reg;
        if (m >= TOTAL) continue;
        #pragma unroll
        for (int j = 0; j < 2; ++j) {
          const int n = n0 + wn + j * 16 + lr;
          const float v = acc[i][j][reg] + b_a[n];
          emb[(size_t)m * INDIM + n] = v;
          emb_h[(size_t)m * INDIM + n] = f2bf(v);
        }
      }
    }
  } else if (bid < 3760) {
    const int pb = bid - 48;
    if (pb < 3456) {
      const int idx = pb * 256 + tid;
      const int k = idx % KPAD, gm = idx / KPAD;
      Ah[idx] = (k < DIN) ? f2bf(Wc[gm * DIN + k]) : (unsigned short)0;
    } else {
      const int i = (pb - 3456) * 256 + tid;
      const float4 v = reinterpret_cast<const float4*>(Wh)[i];
      us4 o; o[0] = f2bf(v.x); o[1] = f2bf(v.y); o[2] = f2bf(v.z); o[3] = f2bf(v.w);
      reinterpret_cast<us4*>(Wh_h)[i] = o;
    }
  } else {
    // ---- fm [16][834][1568] fp32 -> BhT [16][1568][864] bf16 ----
    const int fb = bid - 3760;
    const int sx = fb % 49, ky = (fb / 49) % 27, b = fb / (49 * 27);
    const int k0 = ky * 32, s0 = sx * 32;
    const int tx = tid & 31, ty = tid >> 5;
    const float* src = fm + (size_t)b * DIN * SS;
    #pragma unroll
    for (int r = 0; r < 4; ++r) {
      const int k = k0 + ty + r * 8;
      tile[ty + r * 8][tx] = (k < DIN) ? src[(size_t)k * SS + s0 + tx] : 0.f;
    }
    __syncthreads();
    unsigned short* dst = BhT + (size_t)b * SS * KPAD;
    #pragma unroll
    for (int r = 0; r < 4; ++r) {
      const int s = s0 + ty + r * 8;
      dst[(size_t)s * KPAD + k0 + tx] = f2bf(tile[tx][ty + r * 8]);
    }
  }
}

// ---------------- ctx GEMM v6: 256x256 tile, 8 waves, 128x64 wave-tile ----------------
// Diagnosis (r8): ctx is LDS-READ-throughput bound, not memory/barrier bound.
// v3's 64x64 wave-tile needs 0.031 B(LDS)/FLOP -> ds_read_b128 port saturates at
// ~28% MfmaUtil. This version: 128x64 wave-tile (8x4 frags) -> 0.023 B/FLOP:
// per CU-step 256 MFMA (~1240 cyc) vs 96 ds_read (~1150 cyc) -> MFMA-limited.
// Schedule: v4-proven single-barrier ring-4 (refill targets the step-(k-1) buffer,
// whose readers finished pre-barrier), counted vmcnt(8), granule-XOR swizzle,
// j-innermost line-completing C-write. Grid 448 = 8 xcd x 2b x 7mt x 4g,
// A-panel consumers consecutive (r8-proven). mt=6 pads M to 1792: A-reads beyond
// row 1567 stay inside ws (garbage feeds only discarded C rows >=1568, as before);
// C-write guarded by m < SPAD.
__global__ __launch_bounds__(512, 2) void ctx_mfma(const unsigned short* __restrict__ Ah,
                                                   const unsigned short* __restrict__ BhT,
                                                   const float* __restrict__ b_c,
                                                   unsigned short* __restrict__ ctxT) {
  __shared__ unsigned short ABuf[4][2][8192];   // [ring][A|B][16KB] = 128 KiB -> 1 block/CU
  const int lin  = blockIdx.x;                  // 448 = 8 xcd * 56
  const int xcd  = lin & 7;
  const int slot = lin >> 3;                    // 0..55
  const int bloc = (slot >= 28) ? 1 : 0;
  const int within = slot - bloc * 28;          // 0..27
  const int b  = xcd * 2 + bloc;
  const int mt = within >> 2;                   // 0..6 (A-panel id; 4 consecutive g-consumers)
  const int g  = within & 3;
  const int m0 = mt * 256;
  const int zout = (g << 4) + b;

  const int tid = threadIdx.x;
  const int w = tid >> 6, lane = tid & 63;
  const int wm = (w >> 2) * 128;                // 2 wave-groups in M
  const int wn = (w & 3) * 64;                  // 4 wave-groups in N
  const int quad = lane >> 4, lr = lane & 15;

  const unsigned short* Ag = BhT + (size_t)b * SS * KPAD + (size_t)m0 * KPAD;
  const unsigned short* Bg = Ah + (size_t)g * 256 * KPAD;

  // DMA source map: linear dest byte o in the 16KB tile -> swizzled (row, k-chunk).
  // 128B line l holds rows {2l, 2l+1} as 8 granules of 16B, stored granule gs = gg ^ (l&7).
  int rS[2], kS[2];
  #pragma unroll
  for (int p = 0; p < 2; ++p) {
    const int o    = p * 8192 + tid * 16;       // bytes, 0..16383
    const int line = o >> 7;                    // 0..127
    const int gs   = (o >> 4) & 7;
    const int gg   = gs ^ (line & 7);
    rS[p] = line * 2 + (gg >> 2);               // 0..255
    kS[p] = (gg & 3) * 8;                       // shorts
  }

  // ds_read offsets (shorts): fragment (row r, k-quad) -> swizzled granule slot
  int offA[8], offB[4];
  #pragma unroll
  for (int i = 0; i < 8; ++i) {
    const int r = wm + i * 16 + lr;
    const int line = r >> 1;
    const int gs = ((r & 1) * 4 + quad) ^ (line & 7);
    offA[i] = line * 64 + gs * 8;
  }
  #pragma unroll
  for (int j = 0; j < 4; ++j) {
    const int r = wn + j * 16 + lr;
    const int line = r >> 1;
    const int gs = ((r & 1) * 4 + quad) ^ (line & 7);
    offB[j] = line * 64 + gs * 8;
  }

  f32x4 acc[8][4];
  #pragma unroll
  for (int i = 0; i < 8; ++i)
    #pragma unroll
    for (int j = 0; j < 4; ++j) acc[i][j] = (f32x4){0.f, 0.f, 0.f, 0.f};

#define CTX_ISSUE(KT, BUF) {                                                          \
    _Pragma("unroll")                                                                 \
    for (int p = 0; p < 2; ++p) {                                                     \
      gload16(Ag + (size_t)rS[p] * KPAD + (KT) * 32 + kS[p],                          \
              &ABuf[BUF][0][p * 4096 + w * 512]);                                     \
      gload16(Bg + (size_t)rS[p] * KPAD + (KT) * 32 + kS[p],                          \
              &ABuf[BUF][1][p * 4096 + w * 512]);                                     \
    } }

#define CTX_BODY(KT, BUF, NBUF, WAITSTR, DOISSUE) {                                   \
    asm volatile(WAITSTR ::: "memory");        /* tile KT landed (in-order vmcnt)  */ \
    __builtin_amdgcn_s_barrier();              /* all waves: KT landed, KT-1 read  */ \
    if (DOISSUE) CTX_ISSUE((KT) + 3, NBUF);    /* refill buf (KT-1)&3 — consumed   */ \
    bf16x8 af[8], bv[4];                                                              \
    _Pragma("unroll")                                                                 \
    for (int j = 0; j < 4; ++j)                                                       \
      bv[j] = *reinterpret_cast<const bf16x8*>(&ABuf[BUF][1][offB[j]]);               \
    _Pragma("unroll")                                                                 \
    for (int i = 0; i < 8; ++i)                                                       \
      af[i] = *reinterpret_cast<const bf16x8*>(&ABuf[BUF][0][offA[i]]);               \
    asm volatile("s_waitcnt lgkmcnt(0)" ::: "memory");                                \
    __builtin_amdgcn_sched_barrier(0);                                                \
    __builtin_amdgcn_s_setprio(1);                                                    \
    _Pragma("unroll")                                                                 \
    for (int i = 0; i < 8; ++i)                                                       \
      _Pragma("unroll")                                                               \
      for (int j = 0; j < 4; ++j)                                                     \
        acc[i][j] = __builtin_amdgcn_mfma_f32_16x16x32_bf16(af[i], bv[j], acc[i][j], 0, 0, 0); \
    __builtin_amdgcn_s_setprio(0);                                                    \
  }

  // prologue: 3 K-tiles in flight (12 vmem ops/thread); buf3 free for step-0 refill
  CTX_ISSUE(0, 0);
  CTX_ISSUE(1, 1);
  CTX_ISSUE(2, 2);

  for (int kt = 0; kt < 24; kt += 4) {
    CTX_BODY(kt,     0, 3, "s_waitcnt vmcnt(8)", 1);
    CTX_BODY(kt + 1, 1, 0, "s_waitcnt vmcnt(8)", 1);
    CTX_BODY(kt + 2, 2, 1, "s_waitcnt vmcnt(8)", 1);
    CTX_BODY(kt + 3, 3, 2, "s_waitcnt vmcnt(8)", 1);
  }
  CTX_BODY(24, 0, 0, "s_waitcnt vmcnt(8)", 0);
  CTX_BODY(25, 1, 0, "s_waitcnt vmcnt(4)", 0);
  CTX_BODY(26, 2, 0, "s_waitcnt vmcnt(0)", 0);

#undef CTX_BODY
#undef CTX_ISSUE

  // C-write: j innermost -> each quad-group's 4 stores complete a 128B span (proven).
  unsigned short* Cz = ctxT + (size_t)zout * SPAD * GF;
  const float* bias = b_c + g * GF;
  float bvj[4];
  #pragma unroll
  for (int j = 0; j < 4; ++j) bvj[j] = bias[wn + j * 16 + lr];
  #pragma unroll
  for (int i = 0; i < 8; ++i) {
    #pragma unroll
    for (int reg = 0; reg < 4; ++reg) {
      const int m = m0 + wm + i * 16 + quad * 4 + reg;
      if (m < SPAD) {
        #pragma unroll
        for (int j = 0; j < 4; ++j) {
          Cz[(size_t)m * GF + wn + j * 16 + lr] = f2bf(acc[i][j][reg] + bvj[j]);
        }
      }
    }
  }
}

// ---------------- fused attention (r1 form — empirically best) ----------------
__global__ __launch_bounds__(256) void att_part(
    const unsigned short* __restrict__ ctxT,
    const unsigned short* __restrict__ emb_h,
    float* __restrict__ Opart,     // [64*8][16][256]
    float* __restrict__ Spart)     // [64*8][32]: 16 M then 16 L
{
  __shared__ unsigned short Cs[4][32 * CROW];
  __shared__ float Ps[4][32][20];
  __shared__ float walpha[4][16];
  __shared__ float wms[4][16], wls[4][16];
  const int sc = blockIdx.x, z = blockIdx.y;
  const int g = z >> 4, b = z & 15;
  const int count = c_counts[b], off = c_offs[b];
  const int t0 = c_t0[sc], t1 = c_t1[sc];
  const int tid = threadIdx.x, wave = tid >> 6, lane = tid & 63;
  const int quad = lane >> 4, lr = lane & 15;
  const unsigned short* Az = ctxT + (size_t)z * SPAD * GF;
  const bool bvalid = (lr < count);
  const unsigned short* Brow = emb_h + (size_t)(off + (bvalid ? lr : 0)) * INDIM + (g << 8);
  unsigned short* myC = &Cs[wave][0];
  const int fbase = quad * 64 + lr * 4;
  const bf16x8 zero8 = (bf16x8)(short)0;

  float O[16][4];
  #pragma unroll
  for (int n = 0; n < 16; ++n)
    #pragma unroll
    for (int j = 0; j < 4; ++j) O[n][j] = 0.f;
  float m_run = -3.0e38f, l_run = 0.f;

  for (int t = t0 + wave; t < t1; t += 4) {
    const int s0 = t * 32;
    #pragma unroll
    for (int q = 0; q < 16; ++q) {
      const int row = 2 * q + (lane >> 5);
      const int col = (lane & 31) * 8;
      const uint4 v = *reinterpret_cast<const uint4*>(Az + (size_t)(s0 + row) * GF + col);
      *reinterpret_cast<uint4*>(&myC[row * CROW + col]) = v;
    }
    f32x4 acc[2] = {(f32x4){0.f,0.f,0.f,0.f}, (f32x4){0.f,0.f,0.f,0.f}};
    #pragma unroll
    for (int kk = 0; kk < 8; ++kk) {
      const int f = kk * 32 + quad * 8;
      bf16x8 bv8 = *reinterpret_cast<const bf16x8*>(Brow + f);
      if (!bvalid) bv8 = zero8;
      #pragma unroll
      for (int i = 0; i < 2; ++i) {
        const bf16x8 av8 = *reinterpret_cast<const bf16x8*>(&myC[(i * 16 + lr) * CROW + f]);
        acc[i] = __builtin_amdgcn_mfma_f32_16x16x32_bf16(av8, bv8, acc[i], 0, 0, 0);
      }
    }
    float mx = acc[0][0];
    #pragma unroll
    for (int i = 0; i < 2; ++i)
      #pragma unroll
      for (int r = 0; r < 4; ++r) mx = fmaxf(mx, acc[i][r]);
    float lsum = 0.f;
    #pragma unroll
    for (int i = 0; i < 2; ++i)
      #pragma unroll
      for (int r = 0; r < 4; ++r) lsum += __expf(acc[i][r] - mx);
    #pragma unroll
    for (int d = 16; d < 64; d <<= 1) {
      const float om = __shfl_xor(mx, d, 64);
      const float ol = __shfl_xor(lsum, d, 64);
      const float M = fmaxf(mx, om);
      lsum = lsum * __expf(mx - M) + ol * __expf(om - M);
      mx = M;
    }
    const float m_new = fmaxf(m_run, mx);
    const float alpha = __expf(m_run - m_new);
    const float beta  = __expf(mx - m_new);
    l_run = alpha * l_run + beta * lsum;
    m_run = m_new;
    if (lane < 16) walpha[wave][lane] = alpha;
    #pragma unroll
    for (int i = 0; i < 2; ++i)
      #pragma unroll
      for (int r = 0; r < 4; ++r) {
        const int sl = i * 16 + quad * 4 + r;
        Ps[wave][sl][lr] = beta * __expf(acc[i][r] - mx);
      }
    float av[16];
    {
      const float4 a0 = *reinterpret_cast<const float4*>(&walpha[wave][0]);
      const float4 a1 = *reinterpret_cast<const float4*>(&walpha[wave][4]);
      const float4 a2 = *reinterpret_cast<const float4*>(&walpha[wave][8]);
      const float4 a3 = *reinterpret_cast<const float4*>(&walpha[wave][12]);
      av[0]=a0.x; av[1]=a0.y; av[2]=a0.z; av[3]=a0.w;
      av[4]=a1.x; av[5]=a1.y; av[6]=a1.z; av[7]=a1.w;
      av[8]=a2.x; av[9]=a2.y; av[10]=a2.z; av[11]=a2.w;
      av[12]=a3.x; av[13]=a3.y; av[14]=a3.z; av[15]=a3.w;
    }
    #pragma unroll
    for (int n = 0; n < 16; ++n)
      #pragma unroll
      for (int j = 0; j < 4; ++j) O[n][j] *= av[n];
    for (int s = 0; s < 32; ++s) {
      const float4 p0 = *reinterpret_cast<const float4*>(&Ps[wave][s][0]);
      const float4 p1 = *reinterpret_cast<const float4*>(&Ps[wave][s][4]);
      const float4 p2 = *reinterpret_cast<const float4*>(&Ps[wave][s][8]);
      const float4 p3 = *reinterpret_cast<const float4*>(&Ps[wave][s][12]);
      const us4 cv = *reinterpret_cast<const us4*>(&myC[s * CROW + fbase]);
      const float c0 = bf2f(cv[0]), c1 = bf2f(cv[1]), c2 = bf2f(cv[2]), c3 = bf2f(cv[3]);
      const float pn[16] = {p0.x,p0.y,p0.z,p0.w, p1.x,p1.y,p1.z,p1.w,
                            p2.x,p2.y,p2.z,p2.w, p3.x,p3.y,p3.z,p3.w};
      #pragma unroll
      for (int n = 0; n < 16; ++n) {
        O[n][0] = fmaf(pn[n], c0, O[n][0]);
        O[n][1] = fmaf(pn[n], c1, O[n][1]);
        O[n][2] = fmaf(pn[n], c2, O[n][2]);
        O[n][3] = fmaf(pn[n], c3, O[n][3]);
      }
    }
  }

  if (lane < 16) { wms[wave][lane] = m_run; wls[wave][lane] = l_run; }
  __syncthreads();
  float* Ob = reinterpret_cast<float*>(&Cs[wave][0]);
  #pragma unroll
  for (int n = 0; n < 16; ++n) {
    const float Mb = fmaxf(fmaxf(wms[0][n], wms[1][n]), fmaxf(wms[2][n], wms[3][n]));
    const float e = __expf(wms[wave][n] - Mb);
    #pragma unroll
    for (int j = 0; j < 4; ++j) Ob[n * 256 + fbase + j] = O[n][j] * e;
  }
  __syncthreads();
  float* Op = Opart + ((size_t)z * 8 + sc) * 4096;
  #pragma unroll
  for (int nn = 0; nn < 4; ++nn) {
    const int n = wave * 4 + nn;
    float4 v = {0.f, 0.f, 0.f, 0.f};
    #pragma unroll
    for (int w = 0; w < 4; ++w) {
      const float4 x = *reinterpret_cast<const float4*>(
          reinterpret_cast<const float*>(&Cs[w][0]) + n * 256 + fbase);
      v.x += x.x; v.y += x.y; v.z += x.z; v.w += x.w;
    }
    *reinterpret_cast<float4*>(Op + n * 256 + fbase) = v;
  }
  if (wave == 0 && lane < 16) {
    const int n = lane;
    const float Mb = fmaxf(fmaxf(wms[0][n], wms[1][n]), fmaxf(wms[2][n], wms[3][n]));
    float Lb = 0.f;
    #pragma unroll
    for (int w = 0; w < 4; ++w) Lb += wls[w][n] * __expf(wms[w][n] - Mb);
    Spart[((size_t)z * 8 + sc) * 32 + n]      = Mb;
    Spart[((size_t)z * 8 + sc) * 32 + 16 + n] = Lb;
  }
}

// combine 8 s-chunk partials -> flat_h = bf16(attn + emb). grid (64 z, 16 n).
__global__ __launch_bounds__(256) void att_combine(
    const float* __restrict__ Opart, const float* __restrict__ Spart,
    const float* __restrict__ emb, unsigned short* __restrict__ flat_h) {
  const int z = blockIdx.x, n = blockIdx.y;
  const int g = z >> 4, b = z & 15;
  const int count = c_counts[b], off = c_offs[b];
  if (n >= count) return;
  const int f = threadIdx.x;
  float M = -3.0e38f;
  #pragma unroll
  for (int sc = 0; sc < 8; ++sc)
    M = fmaxf(M, Spart[((size_t)z * 8 + sc) * 32 + n]);
  float L = 0.f, acc = 0.f;
  #pragma unroll
  for (int sc = 0; sc < 8; ++sc) {
    const float e = __expf(Spart[((size_t)z * 8 + sc) * 32 + n] - M);
    L += e * Spart[((size_t)z * 8 + sc) * 32 + 16 + n];
    acc += e * Opart[((size_t)z * 8 + sc) * 4096 + n * 256 + f];
  }
  const int t = off + n;
  const int col = (g << 8) + f;
  flat_h[t * INDIM + col] = f2bf(acc / L + emb[t * INDIM + col]);
}

// ---------------- head: bf16 MFMA, out = relu(flat_h @ W_h^T) ----------------
__global__ __launch_bounds__(256) void head_mfma(const unsigned short* __restrict__ flat_h,
                                                 const unsigned short* __restrict__ Wh_h,
                                                 float* __restrict__ out) {
  __shared__ unsigned short As[64 * 40];
  __shared__ unsigned short Bs[64 * 40];
  const int g = blockIdx.z;
  const int n0 = blockIdx.x * 64, m0 = blockIdx.y * 64;
  const int tid = threadIdx.x;
  const int wave = tid >> 6, lane = tid & 63;
  const int wm = (wave >> 1) * 32, wn = (wave & 1) * 32;
  const int quad = lane >> 4, lr = lane & 15;
  const int r = tid >> 2, ko = (tid & 3) * 8;

  const unsigned short* Ag = flat_h + (size_t)m0 * INDIM + g * GF;
  const unsigned short* Bg = Wh_h + (size_t)g * GF * GF + (size_t)n0 * GF;

  f32x4 acc[2][2];
  #pragma unroll
  for (int i = 0; i < 2; ++i)
    #pragma unroll
    for (int j = 0; j < 2; ++j) acc[i][j] = (f32x4){0.f, 0.f, 0.f, 0.f};

  const uint4 zero4 = {0u, 0u, 0u, 0u};
  uint4 ra, rb;
  ra = (m0 + r < TOTAL) ? *reinterpret_cast<const uint4*>(Ag + (size_t)r * INDIM + ko) : zero4;
  rb = *reinterpret_cast<const uint4*>(Bg + (size_t)r * GF + ko);

  for (int kt = 0; kt < 8; ++kt) {
    __syncthreads();
    *reinterpret_cast<uint4*>(&As[r * 40 + ko]) = ra;
    *reinterpret_cast<uint4*>(&Bs[r * 40 + ko]) = rb;
    __syncthreads();
    if (kt < 7) {
      const int k0 = (kt + 1) * 32;
      ra = (m0 + r < TOTAL) ? *reinterpret_cast<const uint4*>(Ag + (size_t)r * INDIM + k0 + ko) : zero4;
      rb = *reinterpret_cast<const uint4*>(Bg + (size_t)r * GF + k0 + ko);
    }
    bf16x8 af[2], bfr[2];
    #pragma unroll
    for (int i = 0; i < 2; ++i)
      af[i] = *reinterpret_cast<const bf16x8*>(&As[(wm + i * 16 + lr) * 40 + quad * 8]);
    #pragma unroll
    for (int j = 0; j < 2; ++j)
      bfr[j] = *reinterpret_cast<const bf16x8*>(&Bs[(wn + j * 16 + lr) * 40 + quad * 8]);
    #pragma unroll
    for (int i = 0; i < 2; ++i)
      #pragma unroll
      for (int j = 0; j < 2; ++j)
        acc[i][j] = __builtin_amdgcn_mfma_f32_16x16x32_bf16(af[i], bfr[j], acc[i][j], 0, 0, 0);
  }

  #pragma unroll
  for (int i = 0; i < 2; ++i) {
    #pragma unroll
    for (int reg = 0; reg < 4; ++reg) {
      const int m = m0 + wm + i * 16 + quad * 4 + reg;
      if (m >= TOTAL) continue;
      #pragma unroll
      for (int j = 0; j < 2; ++j) {
        const int n = n0 + wn + j * 16 + lr;
        out[(size_t)m * INDIM + g * GF + n] = fmaxf(acc[i][j][reg], 0.f);
      }
    }
  }
}

extern "C" void kernel_launch(void* const* d_in, const int* in_sizes, int n_in,
                              void* d_out, int out_size, void* d_ws, size_t ws_size,
                              hipStream_t stream) {
  (void)in_sizes; (void)n_in; (void)out_size; (void)ws_size;
  const float* actor = (const float*)d_in[0];
  const float* fmap  = (const float*)d_in[1];
  const float* W_a   = (const float*)d_in[2];
  const float* b_a   = (const float*)d_in[3];
  const float* W_c   = (const float*)d_in[4];
  const float* b_c   = (const float*)d_in[5];
  const float* W_h   = (const float*)d_in[6];
  float* out = (float*)d_out;
  char* ws = (char*)d_ws;

  float* emb             = (float*)(ws);                        // 655,360 B
  unsigned short* flat_h = (unsigned short*)(ws + 655360);      // 327,680 B
  unsigned short* emb_h  = (unsigned short*)(ws + 983040);      // 327,680 B
  float* Spart           = (float*)(ws + 1310720);              // 65,536 B
  unsigned short* ctxT   = (unsigned short*)(ws + 1376256);     // 54,525,952 B
  unsigned short* Ah     = (unsigned short*)(ws + 55902208);    // 1,769,472 B
  unsigned short* BhT    = (unsigned short*)(ws + 57671680);    // 43,352,064 B
  float* Opart           = (float*)(ws + 57671680);             // 33,554,432 B, aliases BhT (time-disjoint)
  unsigned short* Wh_h   = (unsigned short*)(ws + 101023744);   // 524,288 B (end 101,548,032)

  // 0) mega-fused front end: emb MFMA + weight packs + fm transpose (r1 form)
  hipLaunchKernelGGL(prep_all, dim3(24928), dim3(256), 0, stream,
                     actor, W_a, b_a, W_c, W_h, fmap,
                     emb, emb_h, Ah, Wh_h, BhT);

  // 1) ctxT via bf16 MFMA, 256x256 tile, 8 waves, single-barrier ring-4, XCD-bound b
  hipLaunchKernelGGL(ctx_mfma, dim3(448), dim3(512), 0, stream, Ah, BhT, b_c, ctxT);

  // 2) fused attention (logits + online softmax + PV), s-split 8 (r1 form)
  hipLaunchKernelGGL(att_part, dim3(8, 64), dim3(256), 0, stream,
                     ctxT, emb_h, Opart, Spart);

  // 3) combine partials -> flat_h = bf16(attn + emb)
  hipLaunchKernelGGL(att_combine, dim3(64, 16), dim3(256), 0, stream,
                     Opart, Spart, emb, flat_h);

  // 4) out = relu(flat_h @ W_h^T)
  hipLaunchKernelGGL(head_mfma, dim3(4, 3, 4), dim3(256), 0, stream,
                     flat_h, Wh_h, out);
}